// Round 2
// baseline (6347.960 us; speedup 1.0000x reference)
//
#include <hip/hip_runtime.h>

#define N_NODES 100000
#define N_EDGES 1600000

__device__ __forceinline__ float sigf(float x) { return 1.f / (1.f + __expf(-x)); }

// ---------------- graph preprocessing ----------------

__global__ void edge_deg_kernel(const int* __restrict__ src, const int* __restrict__ dst,
                                const float* __restrict__ w,
                                float* __restrict__ degO, float* __restrict__ degI,
                                int* __restrict__ cntO, int* __restrict__ cntI)
{
    int i = blockIdx.x * 256 + threadIdx.x;
    if (i >= N_EDGES) return;
    int s = src[i], d = dst[i];
    float wv = w[i];
    atomicAdd(&degO[s], wv);
    atomicAdd(&degI[d], wv);
    atomicAdd(&cntI[s], 1);   // pin CSR grouped by src
    atomicAdd(&cntO[d], 1);   // pout CSR grouped by dst
}

__global__ void invert_kernel(float* __restrict__ p, int n)
{
    int i = blockIdx.x * 256 + threadIdx.x;
    if (i >= n) return;
    float v = p[i];
    p[i] = (v > 0.f) ? 1.f / v : 0.f;
}

// one block per array; block-wide running exclusive scan
__global__ __launch_bounds__(1024) void scan2_kernel(const int* __restrict__ cntA, int* __restrict__ rpA,
                                                     const int* __restrict__ cntB, int* __restrict__ rpB,
                                                     int n)
{
    const int* cnt = blockIdx.x ? cntB : cntA;
    int* rp = blockIdx.x ? rpB : rpA;
    __shared__ int wsum[16];
    __shared__ int carry;
    int tid = threadIdx.x, lane = tid & 63, wid = tid >> 6;
    if (tid == 0) { rp[0] = 0; carry = 0; }
    __syncthreads();
    for (int base = 0; base < n; base += 1024) {
        int idx = base + tid;
        int x = (idx < n) ? cnt[idx] : 0;
        #pragma unroll
        for (int off = 1; off < 64; off <<= 1) {
            int y = __shfl_up(x, off);
            if (lane >= off) x += y;
        }
        if (lane == 63) wsum[wid] = x;
        __syncthreads();
        if (wid == 0 && lane < 16) {
            int y = wsum[lane];
            #pragma unroll
            for (int off = 1; off < 16; off <<= 1) {
                int z = __shfl_up(y, off);
                if (lane >= off) y += z;
            }
            wsum[lane] = y;
        }
        __syncthreads();
        int tot = x + (wid ? wsum[wid - 1] : 0) + carry;
        if (idx < n) rp[idx + 1] = tot;
        __syncthreads();
        if (tid == 1023) carry = tot;
        __syncthreads();
    }
}

__global__ void fill_kernel(const int* __restrict__ src, const int* __restrict__ dst,
                            const int* __restrict__ rpO, const int* __restrict__ rpI,
                            int* __restrict__ curO, int* __restrict__ curI,
                            int* __restrict__ adjO, int* __restrict__ adjI)
{
    int i = blockIdx.x * 256 + threadIdx.x;
    if (i >= N_EDGES) return;
    int s = src[i], d = dst[i];
    int p = atomicAdd(&curO[d], 1); adjO[rpO[d] + p] = s;
    int q = atomicAdd(&curI[s], 1); adjI[rpI[s] + q] = d;
}

// ---------------- weight preprocessing ----------------
// in: W [3][2][3][C][64]; out: [3][C][320] with column blocks:
// 0: W00+W10-W02-W12, 1: W01, 2: W02, 3: W11, 4: W12
__global__ void build_wcat_kernel(const float* __restrict__ W, float* __restrict__ outw, int C)
{
    int total = 3 * C * 320;
    int idx = blockIdx.x * 256 + threadIdx.x;
    if (idx >= total) return;
    int o = idx & 63;
    int rest = idx >> 6;
    int blk = rest % 5;
    int gc = rest / 5;
    int c = gc % C;
    int g = gc / C;
    #define WV(d, k) W[((((g * 2 + (d)) * 3 + (k)) * C + c) << 6) + o]
    float val;
    if (blk == 0)      val = WV(0, 0) + WV(1, 0) - WV(0, 2) - WV(1, 2);
    else if (blk == 1) val = WV(0, 1);
    else if (blk == 2) val = WV(0, 2);
    else if (blk == 3) val = WV(1, 1);
    else               val = WV(1, 2);
    #undef WV
    outw[idx] = val;
}

__global__ void extract_xs_kernel(const float* __restrict__ x, float* __restrict__ xs)
{
    int i = blockIdx.x * 256 + threadIdx.x;
    if (i >= 2 * N_NODES) return;
    xs[i] = x[(size_t)(i >> 1) * 24 + (i & 1)];  // x[:, :, 0, :] of (4,25000,12,2)
}

// ---------------- propagation (CSR, wave per node, lane = channel) ----------------
// out[node] = sum_{nb in adj[node]} scale[nb] * u[nb]  (+ addv[node]); addv may alias out.
__global__ __launch_bounds__(256) void prop_kernel(const int* __restrict__ rp, const int* __restrict__ adj,
                                                   const float* __restrict__ scale, const float* __restrict__ u,
                                                   float* __restrict__ out, const float* __restrict__ addv)
{
    int node = (blockIdx.x << 2) + (threadIdx.x >> 6);
    int lane = threadIdx.x & 63;
    int beg = rp[node], end = rp[node + 1];
    float acc = 0.f;
    int e = beg;
    for (; e + 1 < end; e += 2) {
        int s0 = adj[e], s1 = adj[e + 1];
        float w0 = scale[s0], w1 = scale[s1];
        float u0 = u[((size_t)s0 << 6) + lane];
        float u1 = u[((size_t)s1 << 6) + lane];
        acc += w0 * u0;
        acc += w1 * u1;
    }
    if (e < end) {
        int s = adj[e];
        acc += scale[s] * u[((size_t)s << 6) + lane];
    }
    size_t o = ((size_t)node << 6) + lane;
    float r = acc;
    if (addv) r += addv[o];
    out[o] = r;
}

// ---------------- GEMM with split A ----------------
// out[N,64] = act( A2[N,64] @ W[F1:F1+64] + A1[N,F1] @ W[0:F1] + beta*addX + bias )
// LDS As columns: [0..64) = A2 (if present), [c1off..c1off+F1) = A1, c1off = A2?64:0.
// W is the gate base (+ column-block offset), row-major with stride 320.
template <int ACT>  // 0 none, 1 sigmoid, 2 tanh
__global__ __launch_bounds__(256) void gemm_kernel(const float* __restrict__ A1, int F1,
                                                   const float* __restrict__ A2,
                                                   const float* __restrict__ W,
                                                   float* __restrict__ out,
                                                   const float* __restrict__ addX, float beta,
                                                   const float* __restrict__ bias)
{
    __shared__ float As[64 * 128];  // row-major [r][k], k XOR-swizzled by ((r&7)<<2)
    __shared__ float Ws[128 * 64];  // k-major [k][c]
    const int M = N_NODES;
    int row0 = blockIdx.x * 64;
    int tid = threadIdx.x;
    int rows = M - row0; if (rows > 64) rows = 64;
    int c1off = A2 ? 64 : 0;
    int K = c1off + F1;

    for (int i = tid; i < (K << 6); i += 256) {
        int k = i >> 6, c = i & 63;
        int wr = (k < c1off) ? (F1 + k) : (k - c1off);  // LDS col -> weight row
        Ws[i] = W[wr * 320 + c];
    }
    if (A2) {
        for (int i = tid; i < 1024; i += 256) {
            int r = i >> 4, c4 = (i & 15) << 2;
            float4 v = make_float4(0.f, 0.f, 0.f, 0.f);
            if (r < rows) v = *(const float4*)&A2[((size_t)(row0 + r) << 6) + c4];
            *(float4*)&As[(r << 7) + (c4 ^ ((r & 7) << 2))] = v;
        }
    }
    if (F1 == 64) {
        for (int i = tid; i < 1024; i += 256) {
            int r = i >> 4, c4 = (i & 15) << 2;
            float4 v = make_float4(0.f, 0.f, 0.f, 0.f);
            if (r < rows) v = *(const float4*)&A1[((size_t)(row0 + r) << 6) + c4];
            int k = c1off + c4;
            *(float4*)&As[(r << 7) + (k ^ ((r & 7) << 2))] = v;
        }
    } else {  // F1 == 2
        for (int i = tid; i < 128; i += 256) {
            int r = i >> 1, c = i & 1;
            float v = (r < rows) ? A1[(size_t)(row0 + r) * 2 + c] : 0.f;
            int k = c1off + c;
            As[(r << 7) + (k ^ ((r & 7) << 2))] = v;
        }
    }
    __syncthreads();

    int tx = tid & 15, ty = tid >> 4;
    int c0 = tx << 2, r0 = ty << 2;
    float acc[4][4] = {};
    #pragma unroll 2
    for (int k = 0; k < K; ++k) {
        float4 b = *(const float4*)&Ws[(k << 6) + c0];
        float a0 = As[((r0 + 0) << 7) + (k ^ (((r0 + 0) & 7) << 2))];
        float a1 = As[((r0 + 1) << 7) + (k ^ (((r0 + 1) & 7) << 2))];
        float a2 = As[((r0 + 2) << 7) + (k ^ (((r0 + 2) & 7) << 2))];
        float a3 = As[((r0 + 3) << 7) + (k ^ (((r0 + 3) & 7) << 2))];
        acc[0][0] += a0 * b.x; acc[0][1] += a0 * b.y; acc[0][2] += a0 * b.z; acc[0][3] += a0 * b.w;
        acc[1][0] += a1 * b.x; acc[1][1] += a1 * b.y; acc[1][2] += a1 * b.z; acc[1][3] += a1 * b.w;
        acc[2][0] += a2 * b.x; acc[2][1] += a2 * b.y; acc[2][2] += a2 * b.z; acc[2][3] += a2 * b.w;
        acc[3][0] += a3 * b.x; acc[3][1] += a3 * b.y; acc[3][2] += a3 * b.z; acc[3][3] += a3 * b.w;
    }

    #pragma unroll
    for (int i = 0; i < 4; ++i) {
        int r = row0 + r0 + i;
        if (r >= M) break;
        float4 v = make_float4(acc[i][0], acc[i][1], acc[i][2], acc[i][3]);
        if (addX) {
            float4 ax = *(const float4*)&addX[((size_t)r << 6) + c0];
            v.x += beta * ax.x; v.y += beta * ax.y; v.z += beta * ax.z; v.w += beta * ax.w;
        }
        if (bias) {
            float4 bb = *(const float4*)&bias[c0];
            v.x += bb.x; v.y += bb.y; v.z += bb.z; v.w += bb.w;
        }
        if (ACT == 1) { v.x = sigf(v.x); v.y = sigf(v.y); v.z = sigf(v.z); v.w = sigf(v.w); }
        else if (ACT == 2) { v.x = tanhf(v.x); v.y = tanhf(v.y); v.z = tanhf(v.z); v.w = tanhf(v.w); }
        *(float4*)&out[((size_t)r << 6) + c0] = v;
    }
}

// ---------------- elementwise glue ----------------

__global__ void mulH_kernel(float* __restrict__ R, const float* __restrict__ h)
{
    int i = blockIdx.x * 256 + threadIdx.x;
    R[i] = R[i] * h[i];
}

__global__ void combine_h0_kernel(const float* __restrict__ Z, const float* __restrict__ T,
                                  float* __restrict__ h, float* __restrict__ hrelu)
{
    int i = blockIdx.x * 256 + threadIdx.x;
    float z = Z[i], t = T[i];
    float v = (1.f - z) * t;
    h[i] = v;
    if (hrelu) hrelu[i] = fmaxf(v, 0.f);
}

// h := relu(z*h + (1-z)*t)   (in place on h)
__global__ void combine_relu_kernel(const float* __restrict__ Z, const float* __restrict__ T,
                                    float* __restrict__ h)
{
    int i = blockIdx.x * 256 + threadIdx.x;
    float z = Z[i], t = T[i];
    float v = z * h[i] + (1.f - z) * t;
    h[i] = fmaxf(v, 0.f);
}

__global__ void combine_final_kernel(const float* __restrict__ Z, const float* __restrict__ T,
                                     const float* __restrict__ hp,
                                     const float* __restrict__ lW, const float* __restrict__ lb,
                                     float* __restrict__ out)
{
    int node = (blockIdx.x << 2) + (threadIdx.x >> 6);
    int lane = threadIdx.x & 63;
    size_t i = ((size_t)node << 6) + lane;
    float z = Z[i], t = T[i];
    float d = z * hp[i] + (1.f - z) * t;
    float s0 = d * lW[lane * 2];
    float s1 = d * lW[lane * 2 + 1];
    #pragma unroll
    for (int off = 32; off > 0; off >>= 1) {
        s0 += __shfl_down(s0, off);
        s1 += __shfl_down(s1, off);
    }
    if (lane == 0) {
        out[node * 2]     = s0 + lb[0];
        out[node * 2 + 1] = s1 + lb[1];
    }
}

// ---------------- driver ----------------

extern "C" void kernel_launch(void* const* d_in, const int* in_sizes, int n_in,
                              void* d_out, int out_size, void* d_ws, size_t ws_size,
                              hipStream_t stream)
{
    (void)in_sizes; (void)n_in; (void)out_size;
    const float* x   = (const float*)d_in[0];
    const int*  eidx = (const int*)d_in[1];
    const float* ew  = (const float*)d_in[2];
    const float* e1W = (const float*)d_in[3];
    const float* e1b = (const float*)d_in[4];
    const float* e2W = (const float*)d_in[5];
    const float* e2b = (const float*)d_in[6];
    const float* d1W = (const float*)d_in[7];
    const float* d1b = (const float*)d_in[8];
    const float* d2W = (const float*)d_in[9];
    const float* d2b = (const float*)d_in[10];
    const float* lW  = (const float*)d_in[11];
    const float* lb  = (const float*)d_in[12];
    const int* src = eidx;
    const int* dst = eidx + N_EDGES;
    const int N = N_NODES, E = N_EDGES;

    char* p = (char*)d_ws;
    auto carve = [&](size_t bytes) { char* r = p; p += (bytes + 255) & ~(size_t)255; return r; };
    float* degblk = (float*)carve((size_t)4 * N * 4);  // do_inv | di_inv | cntO | cntI
    float* do_inv = degblk;
    float* di_inv = degblk + N;
    int* cntO = (int*)(degblk + 2 * N);
    int* cntI = cntO + N;
    int* rpO  = (int*)carve((size_t)(N + 1) * 4);
    int* rpI  = (int*)carve((size_t)(N + 1) * 4);
    int* adjO = (int*)carve((size_t)E * 4);
    int* adjI = (int*)carve((size_t)E * 4);
    float* wcE1 = (float*)carve((size_t)3 * 66 * 320 * 4);
    float* wcE2 = (float*)carve((size_t)3 * 128 * 320 * 4);
    float* wcD1 = (float*)carve((size_t)3 * 66 * 320 * 4);
    float* wcD2 = (float*)carve((size_t)3 * 128 * 320 * 4);
    float* xs = (float*)carve((size_t)N * 2 * 4);
    size_t NH = (size_t)N * 64 * 4;
    float* h1  = (float*)carve(NH);   // h_enc1, later overwritten in place with relu(dec1 out)
    float* h1r = (float*)carve(NH);   // relu(h_enc1)
    float* h2  = (float*)carve(NH);   // h_enc2
    float* gZ  = (float*)carve(NH);
    float* gR  = (float*)carve(NH);   // R gate, then R*h (candidate's A2)
    float* t0  = (float*)carve(NH);
    float* t1  = (float*)carve(NH);
    float* t2  = (float*)carve(NH);

    // Workspace guard: if insufficient, launch nothing -> clean absmax failure
    // (diagnostic: distinguishes ws exhaustion from a kernel fault).
    size_t needed = (size_t)(p - (char*)d_ws);
    if (needed > ws_size) return;

    // --- graph prep ---
    hipMemsetAsync(degblk, 0, (size_t)4 * N * 4, stream);
    int eg = (E + 255) / 256;
    edge_deg_kernel<<<eg, 256, 0, stream>>>(src, dst, ew, do_inv, di_inv, cntO, cntI);
    invert_kernel<<<(2 * N + 255) / 256, 256, 0, stream>>>(do_inv, 2 * N);
    scan2_kernel<<<2, 1024, 0, stream>>>(cntO, rpO, cntI, rpI, N);
    hipMemsetAsync(cntO, 0, (size_t)2 * N * 4, stream);
    fill_kernel<<<eg, 256, 0, stream>>>(src, dst, rpO, rpI, cntO, cntI, adjO, adjI);

    build_wcat_kernel<<<(3 * 66 * 320 + 255) / 256, 256, 0, stream>>>(e1W, wcE1, 66);
    build_wcat_kernel<<<(3 * 128 * 320 + 255) / 256, 256, 0, stream>>>(e2W, wcE2, 128);
    build_wcat_kernel<<<(3 * 66 * 320 + 255) / 256, 256, 0, stream>>>(d1W, wcD1, 66);
    build_wcat_kernel<<<(3 * 128 * 320 + 255) / 256, 256, 0, stream>>>(d2W, wcD2, 128);
    extract_xs_kernel<<<(2 * N + 255) / 256, 256, 0, stream>>>(x, xs);

    auto gemm = [&](const float* A1, int F1, const float* A2, const float* W, float* o,
                    const float* addX, float beta, const float* bias, int act) {
        dim3 g((N + 63) / 64);
        if (act == 0)      gemm_kernel<0><<<g, 256, 0, stream>>>(A1, F1, A2, W, o, addX, beta, bias);
        else if (act == 1) gemm_kernel<1><<<g, 256, 0, stream>>>(A1, F1, A2, W, o, addX, beta, bias);
        else               gemm_kernel<2><<<g, 256, 0, stream>>>(A1, F1, A2, W, o, addX, beta, bias);
    };
    auto prop = [&](const int* rp, const int* adj, const float* sc, const float* u,
                    float* o, const float* addv) {
        prop_kernel<<<N / 4, 256, 0, stream>>>(rp, adj, sc, u, o, addv);
    };
    // one dconv gate:
    // out = act( A@Wc0 + P_o(A@Wc1 + 2 P_o(A@Wc2)) + P_i(A@Wc3 + 2 P_i(A@Wc4)) + b )
    auto dgate = [&](const float* A1, int F1, const float* A2, const float* Wg,
                     const float* bias, int act, float* outp) {
        gemm(A1, F1, A2, Wg + 2 * 64, t0, nullptr, 0.f, nullptr, 0);  // t0 = A@W02
        prop(rpO, adjO, do_inv, t0, t1, nullptr);                     // t1 = P_o(t0)
        gemm(A1, F1, A2, Wg + 1 * 64, t2, t1, 2.f, nullptr, 0);       // t2 = A@W01 + 2 t1
        prop(rpO, adjO, do_inv, t2, t0, nullptr);                     // t0 = ho
        gemm(A1, F1, A2, Wg + 4 * 64, t1, nullptr, 0.f, nullptr, 0);  // t1 = A@W12
        prop(rpI, adjI, di_inv, t1, t2, nullptr);                     // t2 = P_i(t1)
        gemm(A1, F1, A2, Wg + 3 * 64, t1, t2, 2.f, nullptr, 0);       // t1 = A@W11 + 2 t2
        prop(rpI, adjI, di_inv, t1, t2, t0);                          // t2 = hi + ho
        gemm(A1, F1, A2, Wg + 0, outp, t2, 1.f, bias, act);           // act(base + t2 + b)
    };

    const int GB = 25000;  // N*64/256 elementwise grid; also N/4 node-wave grid
    const size_t GE1 = (size_t)66 * 320, GE2 = (size_t)128 * 320;

    // enc1: h = 0 -> skip R gate
    dgate(xs, 2, nullptr, wcE1, e1b, 1, gZ);
    dgate(xs, 2, nullptr, wcE1 + 2 * GE1, e1b + 128, 2, gR);
    combine_h0_kernel<<<GB, 256, 0, stream>>>(gZ, gR, h1, h1r);
    // enc2: input relu(h_enc1), h = 0
    dgate(h1r, 64, nullptr, wcE2, e2b, 1, gZ);
    dgate(h1r, 64, nullptr, wcE2 + 2 * GE2, e2b + 128, 2, gR);
    combine_h0_kernel<<<GB, 256, 0, stream>>>(gZ, gR, h2, nullptr);
    // dec1: x = xs, h = h_enc1 (h1)
    dgate(xs, 2, h1, wcD1, d1b, 1, gZ);
    dgate(xs, 2, h1, wcD1 + GE1, d1b + 64, 1, gR);
    mulH_kernel<<<GB, 256, 0, stream>>>(gR, h1);
    dgate(xs, 2, gR, wcD1 + 2 * GE1, d1b + 128, 2, t0);
    combine_relu_kernel<<<GB, 256, 0, stream>>>(gZ, t0, h1);  // h1 := hA
    // dec2: x = hA (h1), h = h_enc2 (h2)
    dgate(h1, 64, h2, wcD2, d2b, 1, gZ);
    dgate(h1, 64, h2, wcD2 + GE2, d2b + 64, 1, gR);
    mulH_kernel<<<GB, 256, 0, stream>>>(gR, h2);
    dgate(h1, 64, gR, wcD2 + 2 * GE2, d2b + 128, 2, t0);
    combine_final_kernel<<<GB, 256, 0, stream>>>(gZ, t0, h2, lW, lb, (float*)d_out);
}

// Round 3
// 3092.589 us; speedup vs baseline: 2.0526x; 2.0526x over previous
//
#include <hip/hip_runtime.h>

#define N_NODES 100000
#define N_EDGES 1600000

typedef _Float16 f16;
typedef _Float16 f16x8 __attribute__((ext_vector_type(8)));
typedef float f32x4 __attribute__((ext_vector_type(4)));

__device__ __forceinline__ float sigf(float x) { return 1.f / (1.f + __expf(-x)); }

// ---------------- graph preprocessing ----------------

__global__ void count_kernel(const int* __restrict__ src, const int* __restrict__ dst,
                             int* __restrict__ cntO, int* __restrict__ cntI)
{
    int i = blockIdx.x * 256 + threadIdx.x;
    if (i >= N_EDGES) return;
    atomicAdd(&cntO[dst[i]], 1);   // pout CSR grouped by dst
    atomicAdd(&cntI[src[i]], 1);   // pin CSR grouped by src
}

// one block per array; block-wide running exclusive scan
__global__ __launch_bounds__(1024) void scan2_kernel(const int* __restrict__ cntA, int* __restrict__ rpA,
                                                     const int* __restrict__ cntB, int* __restrict__ rpB,
                                                     int n)
{
    const int* cnt = blockIdx.x ? cntB : cntA;
    int* rp = blockIdx.x ? rpB : rpA;
    __shared__ int wsum[16];
    __shared__ int carry;
    int tid = threadIdx.x, lane = tid & 63, wid = tid >> 6;
    if (tid == 0) { rp[0] = 0; carry = 0; }
    __syncthreads();
    for (int base = 0; base < n; base += 1024) {
        int idx = base + tid;
        int x = (idx < n) ? cnt[idx] : 0;
        #pragma unroll
        for (int off = 1; off < 64; off <<= 1) {
            int y = __shfl_up(x, off);
            if (lane >= off) x += y;
        }
        if (lane == 63) wsum[wid] = x;
        __syncthreads();
        if (wid == 0 && lane < 16) {
            int y = wsum[lane];
            #pragma unroll
            for (int off = 1; off < 16; off <<= 1) {
                int z = __shfl_up(y, off);
                if (lane >= off) y += z;
            }
            wsum[lane] = y;
        }
        __syncthreads();
        int tot = x + (wid ? wsum[wid - 1] : 0) + carry;
        if (idx < n) rp[idx + 1] = tot;
        __syncthreads();
        if (tid == 1023) carry = tot;
        __syncthreads();
    }
}

__global__ void fill_kernel(const int* __restrict__ src, const int* __restrict__ dst,
                            const float* __restrict__ ew,
                            const int* __restrict__ rpO, const int* __restrict__ rpI,
                            int* __restrict__ curO, int* __restrict__ curI,
                            int* __restrict__ adjO, float* __restrict__ wO,
                            int* __restrict__ adjI, float* __restrict__ wI)
{
    int i = blockIdx.x * 256 + threadIdx.x;
    if (i >= N_EDGES) return;
    int s = src[i], d = dst[i];
    float w = ew[i];
    int p = atomicAdd(&curO[d], 1); int o1 = rpO[d] + p; adjO[o1] = s; wO[o1] = w;
    int q = atomicAdd(&curI[s], 1); int o2 = rpI[s] + q; adjI[o2] = d; wI[o2] = w;
}

// deg_out[n] = sum ew over edges with src=n (wI segment); deg_in over dst=n (wO segment)
__global__ void deg_inv_kernel(const int* __restrict__ rpO, const float* __restrict__ wO,
                               const int* __restrict__ rpI, const float* __restrict__ wI,
                               float* __restrict__ do_inv, float* __restrict__ di_inv)
{
    int n = blockIdx.x * 256 + threadIdx.x;
    if (n >= N_NODES) return;
    float s = 0.f;
    for (int e = rpI[n]; e < rpI[n + 1]; ++e) s += wI[e];
    do_inv[n] = (s > 0.f) ? 1.f / s : 0.f;
    float t = 0.f;
    for (int e = rpO[n]; e < rpO[n + 1]; ++e) t += wO[e];
    di_inv[n] = (t > 0.f) ? 1.f / t : 0.f;
}

// ---------------- weight preprocessing ----------------
// Step-major fp16 weights for the MFMA GEMM: wstep[s][c][32k].
// Steps 0..9: part p=s>>1 (p: 0=v,1=t1o,2=t2o,3=t1i,4=t2i), W rows rowBase+(s&1)*32+k32.
// Step 10 (XSTEP): k<10 -> p=k>>1, W row = k&1 (x channels); else 0.
__global__ void prep_w(const float* __restrict__ W, int C, int rowBase,
                       int gLo, int gHi, int COLS, int XSTEP, f16* __restrict__ outw)
{
    int total = (10 + XSTEP) * COLS * 32;
    int idx = blockIdx.x * 256 + threadIdx.x;
    if (idx >= total) return;
    int k32 = idx & 31;
    int c = (idx >> 5) % COLS;
    int s = (idx >> 5) / COLS;
    int g = (c < 64 || gHi < 0) ? gLo : gHi;
    int col = (c >= 64) ? c - 64 : c;
    int p, r;
    if (s < 10) { p = s >> 1; r = rowBase + ((s & 1) << 5) + k32; }
    else {
        if (k32 < 10) { p = k32 >> 1; r = k32 & 1; }
        else { outw[idx] = (f16)0.f; return; }
    }
    auto wv = [&](int d, int k) {
        return W[((((size_t)(g * 2 + d) * 3 + k) * C + r) << 6) + col];
    };
    float val;
    if (p == 0)      val = wv(0, 0) + wv(1, 0);
    else if (p == 1) val = wv(0, 1);
    else if (p == 2) val = wv(0, 2);
    else if (p == 3) val = wv(1, 1);
    else             val = wv(1, 2);
    outw[idx] = (f16)val;
}

// enc1 weights fp32 [10][128]: cols 0-63 gate z(0), 64-127 gate h(2); C=66, x rows 0..1
__global__ void prep_enc1w(const float* __restrict__ W, float* __restrict__ outw)
{
    int idx = blockIdx.x * 256 + threadIdx.x;
    if (idx >= 1280) return;
    int c = idx & 127, k = idx >> 7;
    int g = (c < 64) ? 0 : 2, col = c & 63;
    int p = k >> 1, r = k & 1;
    const int C = 66;
    auto wv = [&](int d, int kk) {
        return W[((((size_t)(g * 2 + d) * 3 + kk) * C + r) << 6) + col];
    };
    float val;
    if (p == 0)      val = wv(0, 0) + wv(1, 0);
    else if (p == 1) val = wv(0, 1);
    else if (p == 2) val = wv(0, 2);
    else if (p == 3) val = wv(1, 1);
    else             val = wv(1, 2);
    outw[idx] = val;
}

// xcat fp16 [N][32]: cols 0-1 = xs, 2-9 filled by prop2, 10-31 zero
__global__ void xcat_init(const float* __restrict__ x, f16* __restrict__ xcat)
{
    int i = blockIdx.x * 256 + threadIdx.x;
    if (i >= N_NODES * 32) return;
    int n = i >> 5, c = i & 31;
    float v = (c < 2) ? x[(size_t)n * 24 + c] : 0.f;  // x[:, :, 0, :] of (4,25000,12,2)
    xcat[i] = (f16)v;
}

// 2-channel propagation inside xcat; write cols disjoint from read cols
__global__ void prop2_kernel(const int* __restrict__ rp, const int* __restrict__ adj,
                             const float* __restrict__ scale, f16* __restrict__ xcat,
                             int cin, int cout, int csub)
{
    int n = blockIdx.x * 256 + threadIdx.x;
    if (n >= N_NODES) return;
    int beg = rp[n], end = rp[n + 1];
    float a0 = 0.f, a1 = 0.f;
    for (int e = beg; e < end; ++e) {
        int s = adj[e];
        float w = scale[s];
        a0 += w * (float)xcat[((size_t)s << 5) + cin];
        a1 += w * (float)xcat[((size_t)s << 5) + cin + 1];
    }
    if (csub >= 0) {
        a0 = 2.f * a0 - (float)xcat[((size_t)n << 5) + csub];
        a1 = 2.f * a1 - (float)xcat[((size_t)n << 5) + csub + 1];
    }
    xcat[((size_t)n << 5) + cout] = (f16)a0;
    xcat[((size_t)n << 5) + cout + 1] = (f16)a1;
}

// ---------------- 64-channel propagation (wave per node, lane = channel) ----------------
// out = P(u) or 2*P(u) - sub (fp32 math, fp16 storage)
__global__ __launch_bounds__(256) void prop16_kernel(const int* __restrict__ rp, const int* __restrict__ adj,
                                                     const float* __restrict__ scale, const f16* __restrict__ u,
                                                     f16* __restrict__ out, const f16* __restrict__ sub)
{
    int node = (blockIdx.x << 2) + (threadIdx.x >> 6);
    int lane = threadIdx.x & 63;
    int beg = rp[node], end = rp[node + 1];
    float acc = 0.f;
    int e = beg;
    for (; e + 1 < end; e += 2) {
        int s0 = adj[e], s1 = adj[e + 1];
        float w0 = scale[s0], w1 = scale[s1];
        float u0 = (float)u[((size_t)s0 << 6) + lane];
        float u1 = (float)u[((size_t)s1 << 6) + lane];
        acc += w0 * u0;
        acc += w1 * u1;
    }
    if (e < end) {
        int s = adj[e];
        acc += scale[s] * (float)u[((size_t)s << 6) + lane];
    }
    size_t o = ((size_t)node << 6) + lane;
    float r = sub ? (2.f * acc - (float)sub[o]) : acc;
    out[o] = (f16)r;
}

// ---------------- MFMA GEMM over virtually-concatenated parts ----------------
// out[N,COLS] = ACT( sum_steps A_s[N,32] @ Wstep_s[32,COLS] + addX + bias )
// Parts (5x [N,64] fp16, 2 steps each) + optional xcat step ([N,32] fp16).
// ACT: 0 none, 1 sigmoid, 2 tanh, 3 sigmoid(cols<64)|tanh(cols>=64)
template <int STEPS, int COLS, int ACT>
__global__ __launch_bounds__(256) void mfma_gemm(
    const f16* __restrict__ p0, const f16* __restrict__ p1, const f16* __restrict__ p2,
    const f16* __restrict__ p3, const f16* __restrict__ p4, const f16* __restrict__ xcat,
    const f16* __restrict__ wstep, const f16* __restrict__ addX,
    const float* __restrict__ biasLo, const float* __restrict__ biasHi,
    f16* __restrict__ out)
{
    __shared__ f16 As[64][40];     // [row][k], pad 40 halves (80B rows -> 2-way banks)
    __shared__ f16 Ws[COLS][40];   // [col][k]
    const int row0 = blockIdx.x * 64;
    const int tid = threadIdx.x;
    const int wave = tid >> 6, lane = tid & 63;
    const int lr = lane & 15, lk = lane >> 4;
    const int ka = lk << 3;

    constexpr int RT = (COLS == 128) ? 4 : 2;
    f32x4 acc[RT][2] = {};

    const f16* parts[5] = { p0, p1, p2, p3, p4 };

    #pragma unroll
    for (int s = 0; s < STEPS; ++s) {
        __syncthreads();
        {   // stage A tile: 64 rows x 32 halves
            int r = tid >> 2, seg = tid & 3;
            int grow = row0 + r;
            const f16* srcp = (s < 10)
                ? parts[s >> 1] + (((size_t)grow << 6) + ((s & 1) << 5) + (seg << 3))
                : xcat + (((size_t)grow << 5) + (seg << 3));
            int4 v = (grow < N_NODES) ? *(const int4*)srcp : make_int4(0, 0, 0, 0);
            *(int4*)&As[r][seg << 3] = v;
        }
        {   // stage W tile: COLS x 32 halves
            for (int q = tid; q < COLS * 4; q += 256) {
                int c = q >> 2, seg = q & 3;
                *(int4*)&Ws[c][seg << 3] =
                    *(const int4*)(wstep + (((size_t)(s * COLS + c) << 5) + (seg << 3)));
            }
        }
        __syncthreads();
        if (COLS == 128) {
            f16x8 b0 = *(const f16x8*)&Ws[wave * 32 + lr][ka];
            f16x8 b1 = *(const f16x8*)&Ws[wave * 32 + 16 + lr][ka];
            #pragma unroll
            for (int rt = 0; rt < RT; ++rt) {
                f16x8 a = *(const f16x8*)&As[rt * 16 + lr][ka];
                acc[rt][0] = __builtin_amdgcn_mfma_f32_16x16x32_f16(a, b0, acc[rt][0], 0, 0, 0);
                acc[rt][1] = __builtin_amdgcn_mfma_f32_16x16x32_f16(a, b1, acc[rt][1], 0, 0, 0);
            }
        } else {
            f16x8 b0 = *(const f16x8*)&Ws[(wave & 1) * 32 + lr][ka];
            f16x8 b1 = *(const f16x8*)&Ws[(wave & 1) * 32 + 16 + lr][ka];
            #pragma unroll
            for (int rt = 0; rt < RT; ++rt) {
                f16x8 a = *(const f16x8*)&As[(wave >> 1) * 32 + rt * 16 + lr][ka];
                acc[rt][0] = __builtin_amdgcn_mfma_f32_16x16x32_f16(a, b0, acc[rt][0], 0, 0, 0);
                acc[rt][1] = __builtin_amdgcn_mfma_f32_16x16x32_f16(a, b1, acc[rt][1], 0, 0, 0);
            }
        }
    }
    // epilogue: D layout col=lane&15, row=(lane>>4)*4+reg
    #pragma unroll
    for (int rt = 0; rt < RT; ++rt) {
        int rbase = (COLS == 128) ? rt * 16 : (wave >> 1) * 32 + rt * 16;
        #pragma unroll
        for (int ct = 0; ct < 2; ++ct) {
            int col = ((COLS == 128) ? wave * 32 : (wave & 1) * 32) + ct * 16 + lr;
            #pragma unroll
            for (int j = 0; j < 4; ++j) {
                int grow = row0 + rbase + lk * 4 + j;
                if (grow >= N_NODES) continue;
                float v = acc[rt][ct][j];
                if (addX)   v += (float)addX[(size_t)grow * COLS + col];
                if (biasLo) v += (col < 64) ? biasLo[col] : biasHi[col - 64];
                if (ACT == 1)      v = sigf(v);
                else if (ACT == 2) v = tanhf(v);
                else if (ACT == 3) v = (col < 64) ? sigf(v) : tanhf(v);
                out[(size_t)grow * COLS + col] = (f16)v;
            }
        }
    }
}

// ---------------- fused enc1 (K=10 VALU GEMM + GRU combine) ----------------
__global__ __launch_bounds__(256) void enc1_kernel(const f16* __restrict__ xcat,
                                                   const float* __restrict__ We1,
                                                   const float* __restrict__ b,
                                                   f16* __restrict__ h1, f16* __restrict__ h1r)
{
    int node = (blockIdx.x << 2) + (threadIdx.x >> 6);
    int lane = threadIdx.x & 63;
    float az = b[lane], at = b[128 + lane];
    #pragma unroll
    for (int k = 0; k < 10; ++k) {
        float xv = (float)xcat[((size_t)node << 5) + k];
        az += xv * We1[k * 128 + lane];
        at += xv * We1[k * 128 + 64 + lane];
    }
    float z = sigf(az), t = tanhf(at);
    float h = (1.f - z) * t;
    size_t o = ((size_t)node << 6) + lane;
    h1[o] = (f16)h;
    h1r[o] = (f16)fmaxf(h, 0.f);
}

// ---------------- elementwise glue ----------------

__global__ void mulH_kernel(const f16* __restrict__ zr, const f16* __restrict__ h,
                            f16* __restrict__ g)
{
    int i = blockIdx.x * 256 + threadIdx.x;
    int n = i >> 6, c = i & 63;
    g[i] = (f16)((float)zr[((size_t)n << 7) + 64 + c] * (float)h[i]);
}

__global__ void combine_h0_kernel(const f16* __restrict__ zh, f16* __restrict__ h)
{
    int i = blockIdx.x * 256 + threadIdx.x;
    int n = i >> 6, c = i & 63;
    float z = (float)zh[((size_t)n << 7) + c];
    float t = (float)zh[((size_t)n << 7) + 64 + c];
    h[i] = (f16)((1.f - z) * t);
}

__global__ void combine_relu_kernel(const f16* __restrict__ zr, const f16* __restrict__ gT,
                                    const f16* __restrict__ hprev, f16* __restrict__ hA)
{
    int i = blockIdx.x * 256 + threadIdx.x;
    int n = i >> 6, c = i & 63;
    float z = (float)zr[((size_t)n << 7) + c];
    float v = z * (float)hprev[i] + (1.f - z) * (float)gT[i];
    hA[i] = (f16)fmaxf(v, 0.f);
}

__global__ __launch_bounds__(256) void final_kernel(const f16* __restrict__ zr, const f16* __restrict__ gT,
                                                    const f16* __restrict__ h2,
                                                    const float* __restrict__ lW, const float* __restrict__ lb,
                                                    float* __restrict__ out)
{
    int node = (blockIdx.x << 2) + (threadIdx.x >> 6);
    int lane = threadIdx.x & 63;
    size_t i = ((size_t)node << 6) + lane;
    float z = (float)zr[((size_t)node << 7) + lane];
    float d = z * (float)h2[i] + (1.f - z) * (float)gT[i];
    float s0 = d * lW[lane * 2];
    float s1 = d * lW[lane * 2 + 1];
    #pragma unroll
    for (int off = 32; off > 0; off >>= 1) {
        s0 += __shfl_down(s0, off);
        s1 += __shfl_down(s1, off);
    }
    if (lane == 0) {
        out[node * 2]     = s0 + lb[0];
        out[node * 2 + 1] = s1 + lb[1];
    }
}

// ---------------- driver ----------------

extern "C" void kernel_launch(void* const* d_in, const int* in_sizes, int n_in,
                              void* d_out, int out_size, void* d_ws, size_t ws_size,
                              hipStream_t stream)
{
    (void)in_sizes; (void)n_in; (void)out_size;
    const float* x   = (const float*)d_in[0];
    const int*  eidx = (const int*)d_in[1];
    const float* ew  = (const float*)d_in[2];
    const float* e1W = (const float*)d_in[3];
    const float* e1b = (const float*)d_in[4];
    const float* e2W = (const float*)d_in[5];
    const float* e2b = (const float*)d_in[6];
    const float* d1W = (const float*)d_in[7];
    const float* d1b = (const float*)d_in[8];
    const float* d2W = (const float*)d_in[9];
    const float* d2b = (const float*)d_in[10];
    const float* lW  = (const float*)d_in[11];
    const float* lb  = (const float*)d_in[12];
    const int* src = eidx;
    const int* dst = eidx + N_EDGES;
    const int N = N_NODES, E = N_EDGES;

    char* p = (char*)d_ws;
    auto carve = [&](size_t bytes) { char* r = p; p += (bytes + 255) & ~(size_t)255; return r; };
    int*   cntO = (int*)carve((size_t)2 * N * 4);         // cntO | cntI (reused as cur)
    int*   cntI = cntO + N;
    int*   rpO  = (int*)carve((size_t)(N + 1) * 4);
    int*   rpI  = (int*)carve((size_t)(N + 1) * 4);
    int*   adjO = (int*)carve((size_t)E * 4);
    int*   adjI = (int*)carve((size_t)E * 4);
    float* wO   = (float*)carve((size_t)E * 4);
    float* wI   = (float*)carve((size_t)E * 4);
    float* do_inv = (float*)carve((size_t)N * 4);
    float* di_inv = (float*)carve((size_t)N * 4);
    f16*   xcat = (f16*)carve((size_t)N * 32 * 2);
    size_t NH = (size_t)N * 64 * 2;
    f16* h1  = (f16*)carve(NH);
    f16* h1r = (f16*)carve(NH);   // reused as hA after enc2
    f16* h2  = (f16*)carve(NH);
    f16* g   = (f16*)carve(NH);
    f16* gT  = (f16*)carve(NH);
    f16* t0  = (f16*)carve(NH);
    f16* t1  = (f16*)carve(NH);
    f16* t2  = (f16*)carve(NH);
    f16* t3  = (f16*)carve(NH);
    f16* zz  = (f16*)carve((size_t)N * 128 * 2);
    f16* pZR = (f16*)carve((size_t)N * 128 * 2);
    f16* pC  = (f16*)carve(NH);
    f16* wE2   = (f16*)carve((size_t)10 * 128 * 32 * 2);
    f16* wD1zr = (f16*)carve((size_t)11 * 128 * 32 * 2);
    f16* wD1c  = (f16*)carve((size_t)11 * 64 * 32 * 2);
    f16* wD2zrA = (f16*)carve((size_t)10 * 128 * 32 * 2);
    f16* wD2zrB = (f16*)carve((size_t)10 * 128 * 32 * 2);
    f16* wD2cA  = (f16*)carve((size_t)10 * 64 * 32 * 2);
    f16* wD2cB  = (f16*)carve((size_t)10 * 64 * 32 * 2);
    float* We1  = (float*)carve((size_t)1280 * 4);

    size_t needed = (size_t)(p - (char*)d_ws);
    if (needed > ws_size) return;   // clean failure (diagnosable) instead of fault

    const int eg = (E + 255) / 256;
    const int ng = (N + 255) / 256;
    const int GB = 25000;           // N*64/256 elementwise grid; N/4 node-wave grid

    // --- graph prep ---
    hipMemsetAsync(cntO, 0, (size_t)2 * N * 4, stream);
    count_kernel<<<eg, 256, 0, stream>>>(src, dst, cntO, cntI);
    scan2_kernel<<<2, 1024, 0, stream>>>(cntO, rpO, cntI, rpI, N);
    hipMemsetAsync(cntO, 0, (size_t)2 * N * 4, stream);
    fill_kernel<<<eg, 256, 0, stream>>>(src, dst, ew, rpO, rpI, cntO, cntI, adjO, wO, adjI, wI);
    deg_inv_kernel<<<ng, 256, 0, stream>>>(rpO, wO, rpI, wI, do_inv, di_inv);

    // --- weight prep ---
    auto wprep = [&](const float* W, int C, int rowBase, int gLo, int gHi, int COLS, int XS, f16* o) {
        int total = (10 + XS) * COLS * 32;
        prep_w<<<(total + 255) / 256, 256, 0, stream>>>(W, C, rowBase, gLo, gHi, COLS, XS, o);
    };
    wprep(e2W, 128, 0,  0, 2, 128, 0, wE2);
    wprep(d1W, 66,  2,  0, 1, 128, 1, wD1zr);
    wprep(d1W, 66,  2,  2, -1, 64, 1, wD1c);
    wprep(d2W, 128, 0,  0, 1, 128, 0, wD2zrA);
    wprep(d2W, 128, 64, 0, 1, 128, 0, wD2zrB);
    wprep(d2W, 128, 0,  2, -1, 64, 0, wD2cA);
    wprep(d2W, 128, 64, 2, -1, 64, 0, wD2cB);
    prep_enc1w<<<5, 256, 0, stream>>>(e1W, We1);

    // --- x features + 2-channel Chebyshev basis ---
    xcat_init<<<(N * 32 + 255) / 256, 256, 0, stream>>>(x, xcat);
    prop2_kernel<<<ng, 256, 0, stream>>>(rpO, adjO, do_inv, xcat, 0, 2, -1);  // t1o
    prop2_kernel<<<ng, 256, 0, stream>>>(rpO, adjO, do_inv, xcat, 2, 4, 0);   // t2o
    prop2_kernel<<<ng, 256, 0, stream>>>(rpI, adjI, di_inv, xcat, 0, 6, -1);  // t1i
    prop2_kernel<<<ng, 256, 0, stream>>>(rpI, adjI, di_inv, xcat, 6, 8, 0);   // t2i

    auto props = [&](const f16* u) {  // t0..t3 = (t1o, t2o, t1i, t2i) of u
        prop16_kernel<<<GB, 256, 0, stream>>>(rpO, adjO, do_inv, u, t0, nullptr);
        prop16_kernel<<<GB, 256, 0, stream>>>(rpO, adjO, do_inv, t0, t1, u);
        prop16_kernel<<<GB, 256, 0, stream>>>(rpI, adjI, di_inv, u, t2, nullptr);
        prop16_kernel<<<GB, 256, 0, stream>>>(rpI, adjI, di_inv, t2, t3, u);
    };
    const int gg = (N + 63) / 64;

    // enc1
    enc1_kernel<<<GB, 256, 0, stream>>>(xcat, We1, e1b, h1, h1r);
    // enc2 (input h1r, h=0)
    props(h1r);
    mfma_gemm<10, 128, 3><<<gg, 256, 0, stream>>>(h1r, t0, t1, t2, t3, nullptr, wE2,
                                                  nullptr, e2b, e2b + 128, zz);
    combine_h0_kernel<<<GB, 256, 0, stream>>>(zz, h2);
    // dec1 (x=xs, h=h1)
    props(h1);
    mfma_gemm<11, 128, 1><<<gg, 256, 0, stream>>>(h1, t0, t1, t2, t3, xcat, wD1zr,
                                                  nullptr, d1b, d1b + 64, zz);
    mulH_kernel<<<GB, 256, 0, stream>>>(zz, h1, g);
    props(g);
    mfma_gemm<11, 64, 2><<<gg, 256, 0, stream>>>(g, t0, t1, t2, t3, xcat, wD1c,
                                                 nullptr, d1b + 128, d1b + 128, gT);
    combine_relu_kernel<<<GB, 256, 0, stream>>>(zz, gT, h1, h1r);  // h1r := hA
    // dec2 (x=hA, h=h2), split K=640 into hA-half then h2-half (chained via fp16 partials)
    props(h1r);
    mfma_gemm<10, 128, 0><<<gg, 256, 0, stream>>>(h1r, t0, t1, t2, t3, nullptr, wD2zrA,
                                                  nullptr, nullptr, nullptr, pZR);
    mfma_gemm<10, 64, 0><<<gg, 256, 0, stream>>>(h1r, t0, t1, t2, t3, nullptr, wD2cA,
                                                 nullptr, nullptr, nullptr, pC);
    props(h2);
    mfma_gemm<10, 128, 1><<<gg, 256, 0, stream>>>(h2, t0, t1, t2, t3, nullptr, wD2zrB,
                                                  pZR, d2b, d2b + 64, zz);
    mulH_kernel<<<GB, 256, 0, stream>>>(zz, h2, g);
    props(g);
    mfma_gemm<10, 64, 2><<<gg, 256, 0, stream>>>(g, t0, t1, t2, t3, nullptr, wD2cB,
                                                 pC, d2b + 128, d2b + 128, gT);
    final_kernel<<<GB, 256, 0, stream>>>(zz, gT, h2, lW, lb, (float*)d_out);
}

// Round 4
// 2206.907 us; speedup vs baseline: 2.8764x; 1.4013x over previous
//
#include <hip/hip_runtime.h>

#define N_NODES 100000
#define N_EDGES 1600000

typedef _Float16 f16;
typedef _Float16 f16x8 __attribute__((ext_vector_type(8)));
typedef float f32x4 __attribute__((ext_vector_type(4)));

__device__ __forceinline__ float sigf(float x) { return 1.f / (1.f + __expf(-x)); }

// ---------------- graph preprocessing ----------------

// Count degrees AND remember each edge's slot (atomic return) so fill needs no atomics.
__global__ void count_kernel(const int* __restrict__ src, const int* __restrict__ dst,
                             int* __restrict__ cntO, int* __restrict__ cntI,
                             int* __restrict__ slotO, int* __restrict__ slotI)
{
    int i = blockIdx.x * 256 + threadIdx.x;
    if (i >= N_EDGES) return;
    slotO[i] = atomicAdd(&cntO[dst[i]], 1);   // pout CSR grouped by dst
    slotI[i] = atomicAdd(&cntI[src[i]], 1);   // pin CSR grouped by src
}

// one block per array; block-wide running exclusive scan
__global__ __launch_bounds__(1024) void scan2_kernel(const int* __restrict__ cntA, int* __restrict__ rpA,
                                                     const int* __restrict__ cntB, int* __restrict__ rpB,
                                                     int n)
{
    const int* cnt = blockIdx.x ? cntB : cntA;
    int* rp = blockIdx.x ? rpB : rpA;
    __shared__ int wsum[16];
    __shared__ int carry;
    int tid = threadIdx.x, lane = tid & 63, wid = tid >> 6;
    if (tid == 0) { rp[0] = 0; carry = 0; }
    __syncthreads();
    for (int base = 0; base < n; base += 1024) {
        int idx = base + tid;
        int x = (idx < n) ? cnt[idx] : 0;
        #pragma unroll
        for (int off = 1; off < 64; off <<= 1) {
            int y = __shfl_up(x, off);
            if (lane >= off) x += y;
        }
        if (lane == 63) wsum[wid] = x;
        __syncthreads();
        if (wid == 0 && lane < 16) {
            int y = wsum[lane];
            #pragma unroll
            for (int off = 1; off < 16; off <<= 1) {
                int z = __shfl_up(y, off);
                if (lane >= off) y += z;
            }
            wsum[lane] = y;
        }
        __syncthreads();
        int tot = x + (wid ? wsum[wid - 1] : 0) + carry;
        if (idx < n) rp[idx + 1] = tot;
        __syncthreads();
        if (tid == 1023) carry = tot;
        __syncthreads();
    }
}

// Scatter packed {neighbor, weight_bits} — no atomics (slots precomputed).
__global__ void fill_kernel(const int* __restrict__ src, const int* __restrict__ dst,
                            const float* __restrict__ ew,
                            const int* __restrict__ rpO, const int* __restrict__ rpI,
                            const int* __restrict__ slotO, const int* __restrict__ slotI,
                            int2* __restrict__ adj2O, int2* __restrict__ adj2I)
{
    int i = blockIdx.x * 256 + threadIdx.x;
    if (i >= N_EDGES) return;
    int s = src[i], d = dst[i];
    int wb = __float_as_int(ew[i]);
    int2 eo; eo.x = s; eo.y = wb;
    adj2O[rpO[d] + slotO[i]] = eo;
    int2 ei; ei.x = d; ei.y = wb;
    adj2I[rpI[s] + slotI[i]] = ei;
}

// Compact int2 CSR -> int adjacency, and compute inverse degrees in the same sweep.
// di_inv[n] = 1/sum w over edges with dst=n (O-CSR); do_inv[n] = 1/sum w over src=n (I-CSR).
__global__ void finalize_kernel(const int* __restrict__ rpO, const int2* __restrict__ adj2O,
                                int* __restrict__ adjO, float* __restrict__ di_inv,
                                const int* __restrict__ rpI, const int2* __restrict__ adj2I,
                                int* __restrict__ adjI, float* __restrict__ do_inv)
{
    int n = blockIdx.x * 256 + threadIdx.x;
    if (n >= N_NODES) return;
    float s = 0.f;
    for (int e = rpO[n]; e < rpO[n + 1]; ++e) {
        int2 v = adj2O[e];
        adjO[e] = v.x;
        s += __int_as_float(v.y);
    }
    di_inv[n] = (s > 0.f) ? 1.f / s : 0.f;
    float t = 0.f;
    for (int e = rpI[n]; e < rpI[n + 1]; ++e) {
        int2 v = adj2I[e];
        adjI[e] = v.x;
        t += __int_as_float(v.y);
    }
    do_inv[n] = (t > 0.f) ? 1.f / t : 0.f;
}

// ---------------- weight preprocessing (Chebyshev-folded) ----------------
// Parts: p0=u (coeff W00+W10-W02-W12), p1=t1o (W01), p2=s2o=P_o(t1o) (2*W02),
//        p3=t1i (W11), p4=s2i (2*W12).
// Step-major fp16 weights: wstep[s][c][32k]. Steps 0..9: p=s>>1, rows rowBase+(s&1)*32+k32.
// Step 10 (XSTEP): k<10 -> p=k>>1, W row = k&1 (x channels); else 0.
__global__ void prep_w(const float* __restrict__ W, int C, int rowBase,
                       int gLo, int gHi, int COLS, int XSTEP, f16* __restrict__ outw)
{
    int total = (10 + XSTEP) * COLS * 32;
    int idx = blockIdx.x * 256 + threadIdx.x;
    if (idx >= total) return;
    int k32 = idx & 31;
    int c = (idx >> 5) % COLS;
    int s = (idx >> 5) / COLS;
    int g = (c < 64 || gHi < 0) ? gLo : gHi;
    int col = (c >= 64) ? c - 64 : c;
    int p, r;
    if (s < 10) { p = s >> 1; r = rowBase + ((s & 1) << 5) + k32; }
    else {
        if (k32 < 10) { p = k32 >> 1; r = k32 & 1; }
        else { outw[idx] = (f16)0.f; return; }
    }
    auto wv = [&](int d, int k) {
        return W[((((size_t)(g * 2 + d) * 3 + k) * C + r) << 6) + col];
    };
    float val;
    if (p == 0)      val = wv(0, 0) + wv(1, 0) - wv(0, 2) - wv(1, 2);
    else if (p == 1) val = wv(0, 1);
    else if (p == 2) val = 2.f * wv(0, 2);
    else if (p == 3) val = wv(1, 1);
    else             val = 2.f * wv(1, 2);
    outw[idx] = (f16)val;
}

// enc1 weights fp32 [10][128]: cols 0-63 gate z(0), 64-127 gate h(2); C=66, x rows 0..1
__global__ void prep_enc1w(const float* __restrict__ W, float* __restrict__ outw)
{
    int idx = blockIdx.x * 256 + threadIdx.x;
    if (idx >= 1280) return;
    int c = idx & 127, k = idx >> 7;
    int g = (c < 64) ? 0 : 2, col = c & 63;
    int p = k >> 1, r = k & 1;
    const int C = 66;
    auto wv = [&](int d, int kk) {
        return W[((((size_t)(g * 2 + d) * 3 + kk) * C + r) << 6) + col];
    };
    float val;
    if (p == 0)      val = wv(0, 0) + wv(1, 0) - wv(0, 2) - wv(1, 2);
    else if (p == 1) val = wv(0, 1);
    else if (p == 2) val = 2.f * wv(0, 2);
    else if (p == 3) val = wv(1, 1);
    else             val = 2.f * wv(1, 2);
    outw[idx] = val;
}

// xcat fp16 [N][32]: cols 0-1 = xs, 2-9 = (t1o, s2o, t1i, s2i), 10-31 zero
__global__ void xcat_init(const float* __restrict__ x, f16* __restrict__ xcat)
{
    int i = blockIdx.x * 256 + threadIdx.x;
    if (i >= N_NODES * 32) return;
    int n = i >> 5, c = i & 31;
    float v = (c < 2) ? x[(size_t)n * 24 + c] : 0.f;  // x[:, :, 0, :] of (4,25000,12,2)
    xcat[i] = (f16)v;
}

// 2-channel pure propagation inside xcat; write cols disjoint from read cols
__global__ void prop2_kernel(const int* __restrict__ rp, const int* __restrict__ adj,
                             const float* __restrict__ scale, f16* __restrict__ xcat,
                             int cin, int cout)
{
    int n = blockIdx.x * 256 + threadIdx.x;
    if (n >= N_NODES) return;
    int beg = rp[n], end = rp[n + 1];
    float a0 = 0.f, a1 = 0.f;
    for (int e = beg; e < end; ++e) {
        int s = adj[e];
        float w = scale[s];
        a0 += w * (float)xcat[((size_t)s << 5) + cin];
        a1 += w * (float)xcat[((size_t)s << 5) + cin + 1];
    }
    xcat[((size_t)n << 5) + cout] = (f16)a0;
    xcat[((size_t)n << 5) + cout + 1] = (f16)a1;
}

// ---------------- dual-direction 64-ch propagation (wave per node, lane = channel) ----
// outO = P_o(uO), outI = P_i(uI); pure gathers, unroll-4 for MLP.
__global__ __launch_bounds__(256) void prop_dual(
    const int* __restrict__ rpO, const int* __restrict__ adjO, const float* __restrict__ sO,
    const int* __restrict__ rpI, const int* __restrict__ adjI, const float* __restrict__ sI,
    const f16* __restrict__ uO, const f16* __restrict__ uI,
    f16* __restrict__ outO, f16* __restrict__ outI)
{
    int node = (blockIdx.x << 2) + (threadIdx.x >> 6);
    int lane = threadIdx.x & 63;
    float accO = 0.f, accI = 0.f;
    {
        int b = rpO[node], e = rpO[node + 1];
        int i = b;
        for (; i + 3 < e; i += 4) {
            int s0 = adjO[i], s1 = adjO[i + 1], s2 = adjO[i + 2], s3 = adjO[i + 3];
            float f0 = (float)uO[((size_t)s0 << 6) + lane];
            float f1 = (float)uO[((size_t)s1 << 6) + lane];
            float f2 = (float)uO[((size_t)s2 << 6) + lane];
            float f3 = (float)uO[((size_t)s3 << 6) + lane];
            accO += sO[s0] * f0 + sO[s1] * f1 + sO[s2] * f2 + sO[s3] * f3;
        }
        for (; i < e; ++i) {
            int s = adjO[i];
            accO += sO[s] * (float)uO[((size_t)s << 6) + lane];
        }
    }
    {
        int b = rpI[node], e = rpI[node + 1];
        int i = b;
        for (; i + 3 < e; i += 4) {
            int s0 = adjI[i], s1 = adjI[i + 1], s2 = adjI[i + 2], s3 = adjI[i + 3];
            float f0 = (float)uI[((size_t)s0 << 6) + lane];
            float f1 = (float)uI[((size_t)s1 << 6) + lane];
            float f2 = (float)uI[((size_t)s2 << 6) + lane];
            float f3 = (float)uI[((size_t)s3 << 6) + lane];
            accI += sI[s0] * f0 + sI[s1] * f1 + sI[s2] * f2 + sI[s3] * f3;
        }
        for (; i < e; ++i) {
            int s = adjI[i];
            accI += sI[s] * (float)uI[((size_t)s << 6) + lane];
        }
    }
    size_t o = ((size_t)node << 6) + lane;
    outO[o] = (f16)accO;
    outI[o] = (f16)accI;
}

// ---------------- MFMA GEMM over virtually-concatenated parts ----------------
// out[N,COLS] = ACT( sum_steps A_s[N,32] @ Wstep_s[32,COLS] + addX + bias )
// Parts (5x [N,64] fp16, 2 steps each) + optional xcat step ([N,32] fp16).
// ACT: 0 none, 1 sigmoid, 2 tanh, 3 sigmoid(cols<64)|tanh(cols>=64)
// addX may alias out (element-wise in-place chaining).
template <int STEPS, int COLS, int ACT>
__global__ __launch_bounds__(256) void mfma_gemm(
    const f16* __restrict__ p0, const f16* __restrict__ p1, const f16* __restrict__ p2,
    const f16* __restrict__ p3, const f16* __restrict__ p4, const f16* __restrict__ xcat,
    const f16* __restrict__ wstep, const f16* __restrict__ addX,
    const float* __restrict__ biasLo, const float* __restrict__ biasHi,
    f16* __restrict__ out)
{
    __shared__ f16 As[64][40];     // [row][k], pad 40 halves
    __shared__ f16 Ws[COLS][40];   // [col][k]
    const int row0 = blockIdx.x * 64;
    const int tid = threadIdx.x;
    const int wave = tid >> 6, lane = tid & 63;
    const int lr = lane & 15, lk = lane >> 4;
    const int ka = lk << 3;

    constexpr int RT = (COLS == 128) ? 4 : 2;
    f32x4 acc[RT][2] = {};

    const f16* parts[5] = { p0, p1, p2, p3, p4 };

    #pragma unroll
    for (int s = 0; s < STEPS; ++s) {
        __syncthreads();
        {   // stage A tile: 64 rows x 32 halves
            int r = tid >> 2, seg = tid & 3;
            int grow = row0 + r;
            const f16* srcp = (s < 10)
                ? parts[s >> 1] + (((size_t)grow << 6) + ((s & 1) << 5) + (seg << 3))
                : xcat + (((size_t)grow << 5) + (seg << 3));
            int4 v = (grow < N_NODES) ? *(const int4*)srcp : make_int4(0, 0, 0, 0);
            *(int4*)&As[r][seg << 3] = v;
        }
        {   // stage W tile: COLS x 32 halves
            for (int q = tid; q < COLS * 4; q += 256) {
                int c = q >> 2, seg = q & 3;
                *(int4*)&Ws[c][seg << 3] =
                    *(const int4*)(wstep + (((size_t)(s * COLS + c) << 5) + (seg << 3)));
            }
        }
        __syncthreads();
        if (COLS == 128) {
            f16x8 b0 = *(const f16x8*)&Ws[wave * 32 + lr][ka];
            f16x8 b1 = *(const f16x8*)&Ws[wave * 32 + 16 + lr][ka];
            #pragma unroll
            for (int rt = 0; rt < RT; ++rt) {
                f16x8 a = *(const f16x8*)&As[rt * 16 + lr][ka];
                acc[rt][0] = __builtin_amdgcn_mfma_f32_16x16x32_f16(a, b0, acc[rt][0], 0, 0, 0);
                acc[rt][1] = __builtin_amdgcn_mfma_f32_16x16x32_f16(a, b1, acc[rt][1], 0, 0, 0);
            }
        } else {
            f16x8 b0 = *(const f16x8*)&Ws[(wave & 1) * 32 + lr][ka];
            f16x8 b1 = *(const f16x8*)&Ws[(wave & 1) * 32 + 16 + lr][ka];
            #pragma unroll
            for (int rt = 0; rt < RT; ++rt) {
                f16x8 a = *(const f16x8*)&As[(wave >> 1) * 32 + rt * 16 + lr][ka];
                acc[rt][0] = __builtin_amdgcn_mfma_f32_16x16x32_f16(a, b0, acc[rt][0], 0, 0, 0);
                acc[rt][1] = __builtin_amdgcn_mfma_f32_16x16x32_f16(a, b1, acc[rt][1], 0, 0, 0);
            }
        }
    }
    // epilogue: D layout col=lane&15, row=(lane>>4)*4+reg
    #pragma unroll
    for (int rt = 0; rt < RT; ++rt) {
        int rbase = (COLS == 128) ? rt * 16 : (wave >> 1) * 32 + rt * 16;
        #pragma unroll
        for (int ct = 0; ct < 2; ++ct) {
            int col = ((COLS == 128) ? wave * 32 : (wave & 1) * 32) + ct * 16 + lr;
            #pragma unroll
            for (int j = 0; j < 4; ++j) {
                int grow = row0 + rbase + lk * 4 + j;
                if (grow >= N_NODES) continue;
                float v = acc[rt][ct][j];
                if (addX)   v += (float)addX[(size_t)grow * COLS + col];
                if (biasLo) v += (col < 64) ? biasLo[col] : biasHi[col - 64];
                if (ACT == 1)      v = sigf(v);
                else if (ACT == 2) v = tanhf(v);
                else if (ACT == 3) v = (col < 64) ? sigf(v) : tanhf(v);
                out[(size_t)grow * COLS + col] = (f16)v;
            }
        }
    }
}

// ---------------- fused enc1 (K=10 VALU GEMM + GRU combine) ----------------
__global__ __launch_bounds__(256) void enc1_kernel(const f16* __restrict__ xcat,
                                                   const float* __restrict__ We1,
                                                   const float* __restrict__ b,
                                                   f16* __restrict__ h1, f16* __restrict__ h1r)
{
    int node = (blockIdx.x << 2) + (threadIdx.x >> 6);
    int lane = threadIdx.x & 63;
    float az = b[lane], at = b[128 + lane];
    #pragma unroll
    for (int k = 0; k < 10; ++k) {
        float xv = (float)xcat[((size_t)node << 5) + k];
        az += xv * We1[k * 128 + lane];
        at += xv * We1[k * 128 + 64 + lane];
    }
    float z = sigf(az), t = tanhf(at);
    float h = (1.f - z) * t;
    size_t o = ((size_t)node << 6) + lane;
    h1[o] = (f16)h;
    h1r[o] = (f16)fmaxf(h, 0.f);
}

// ---------------- elementwise glue ----------------

__global__ void mulH_kernel(const f16* __restrict__ zr, const f16* __restrict__ h,
                            f16* __restrict__ g)
{
    int i = blockIdx.x * 256 + threadIdx.x;
    int n = i >> 6, c = i & 63;
    g[i] = (f16)((float)zr[((size_t)n << 7) + 64 + c] * (float)h[i]);
}

__global__ void combine_h0_kernel(const f16* __restrict__ zh, f16* __restrict__ h)
{
    int i = blockIdx.x * 256 + threadIdx.x;
    int n = i >> 6, c = i & 63;
    float z = (float)zh[((size_t)n << 7) + c];
    float t = (float)zh[((size_t)n << 7) + 64 + c];
    h[i] = (f16)((1.f - z) * t);
}

__global__ void combine_relu_kernel(const f16* __restrict__ zr, const f16* __restrict__ gT,
                                    const f16* __restrict__ hprev, f16* __restrict__ hA)
{
    int i = blockIdx.x * 256 + threadIdx.x;
    int n = i >> 6, c = i & 63;
    float z = (float)zr[((size_t)n << 7) + c];
    float v = z * (float)hprev[i] + (1.f - z) * (float)gT[i];
    hA[i] = (f16)fmaxf(v, 0.f);
}

__global__ __launch_bounds__(256) void final_kernel(const f16* __restrict__ zr, const f16* __restrict__ gT,
                                                    const f16* __restrict__ h2,
                                                    const float* __restrict__ lW, const float* __restrict__ lb,
                                                    float* __restrict__ out)
{
    int node = (blockIdx.x << 2) + (threadIdx.x >> 6);
    int lane = threadIdx.x & 63;
    size_t i = ((size_t)node << 6) + lane;
    float z = (float)zr[((size_t)node << 7) + lane];
    float d = z * (float)h2[i] + (1.f - z) * (float)gT[i];
    float s0 = d * lW[lane * 2];
    float s1 = d * lW[lane * 2 + 1];
    #pragma unroll
    for (int off = 32; off > 0; off >>= 1) {
        s0 += __shfl_down(s0, off);
        s1 += __shfl_down(s1, off);
    }
    if (lane == 0) {
        out[node * 2]     = s0 + lb[0];
        out[node * 2 + 1] = s1 + lb[1];
    }
}

// ---------------- driver ----------------

extern "C" void kernel_launch(void* const* d_in, const int* in_sizes, int n_in,
                              void* d_out, int out_size, void* d_ws, size_t ws_size,
                              hipStream_t stream)
{
    (void)in_sizes; (void)n_in; (void)out_size;
    const float* x   = (const float*)d_in[0];
    const int*  eidx = (const int*)d_in[1];
    const float* ew  = (const float*)d_in[2];
    const float* e1W = (const float*)d_in[3];
    const float* e1b = (const float*)d_in[4];
    const float* e2W = (const float*)d_in[5];
    const float* e2b = (const float*)d_in[6];
    const float* d1W = (const float*)d_in[7];
    const float* d1b = (const float*)d_in[8];
    const float* d2W = (const float*)d_in[9];
    const float* d2b = (const float*)d_in[10];
    const float* lW  = (const float*)d_in[11];
    const float* lb  = (const float*)d_in[12];
    const int* src = eidx;
    const int* dst = eidx + N_EDGES;
    const int N = N_NODES, E = N_EDGES;

    char* p = (char*)d_ws;
    auto carve = [&](size_t bytes) { char* r = p; p += (bytes + 255) & ~(size_t)255; return r; };
    int*   cntO  = (int*)carve((size_t)2 * N * 4);
    int*   cntI  = cntO + N;
    int*   rpO   = (int*)carve((size_t)(N + 1) * 4);
    int*   rpI   = (int*)carve((size_t)(N + 1) * 4);
    int*   slotO = (int*)carve((size_t)E * 4);   // later reused as adjO
    int*   slotI = (int*)carve((size_t)E * 4);   // later reused as adjI
    int2*  adj2O = (int2*)carve((size_t)E * 8);
    int2*  adj2I = (int2*)carve((size_t)E * 8);
    float* do_inv = (float*)carve((size_t)N * 4);
    float* di_inv = (float*)carve((size_t)N * 4);
    f16*   xcat = (f16*)carve((size_t)N * 32 * 2);
    size_t NH = (size_t)N * 64 * 2;
    f16* h1  = (f16*)carve(NH);
    f16* h1r = (f16*)carve(NH);   // reused as hA after enc2
    f16* h2  = (f16*)carve(NH);
    f16* g   = (f16*)carve(NH);
    f16* gT  = (f16*)carve(NH);
    f16* t0  = (f16*)carve(NH);   // t1o
    f16* t1  = (f16*)carve(NH);   // s2o
    f16* t2  = (f16*)carve(NH);   // t1i
    f16* t3  = (f16*)carve(NH);   // s2i
    f16* zz  = (f16*)carve((size_t)N * 128 * 2);
    f16* wE2   = (f16*)carve((size_t)10 * 128 * 32 * 2);
    f16* wD1zr = (f16*)carve((size_t)11 * 128 * 32 * 2);
    f16* wD1c  = (f16*)carve((size_t)11 * 64 * 32 * 2);
    f16* wD2zrA = (f16*)carve((size_t)10 * 128 * 32 * 2);
    f16* wD2zrB = (f16*)carve((size_t)10 * 128 * 32 * 2);
    f16* wD2cA  = (f16*)carve((size_t)10 * 64 * 32 * 2);
    f16* wD2cB  = (f16*)carve((size_t)10 * 64 * 32 * 2);
    float* We1  = (float*)carve((size_t)1280 * 4);

    size_t needed = (size_t)(p - (char*)d_ws);
    if (needed > ws_size) return;   // clean failure (diagnosable) instead of fault

    const int eg = (E + 255) / 256;
    const int ng = (N + 255) / 256;
    const int GB = 25000;           // N*64/256 elementwise grid; N/4 node-wave grid

    // --- graph prep ---
    hipMemsetAsync(cntO, 0, (size_t)2 * N * 4, stream);
    count_kernel<<<eg, 256, 0, stream>>>(src, dst, cntO, cntI, slotO, slotI);
    scan2_kernel<<<2, 1024, 0, stream>>>(cntO, rpO, cntI, rpI, N);
    fill_kernel<<<eg, 256, 0, stream>>>(src, dst, ew, rpO, rpI, slotO, slotI, adj2O, adj2I);
    int* adjO = slotO;  // slot arrays dead after fill; reuse as compact adjacency
    int* adjI = slotI;
    finalize_kernel<<<ng, 256, 0, stream>>>(rpO, adj2O, adjO, di_inv, rpI, adj2I, adjI, do_inv);

    // --- weight prep ---
    auto wprep = [&](const float* W, int C, int rowBase, int gLo, int gHi, int COLS, int XS, f16* o) {
        int total = (10 + XS) * COLS * 32;
        prep_w<<<(total + 255) / 256, 256, 0, stream>>>(W, C, rowBase, gLo, gHi, COLS, XS, o);
    };
    wprep(e2W, 128, 0,  0, 2, 128, 0, wE2);
    wprep(d1W, 66,  2,  0, 1, 128, 1, wD1zr);
    wprep(d1W, 66,  2,  2, -1, 64, 1, wD1c);
    wprep(d2W, 128, 0,  0, 1, 128, 0, wD2zrA);
    wprep(d2W, 128, 64, 0, 1, 128, 0, wD2zrB);
    wprep(d2W, 128, 0,  2, -1, 64, 0, wD2cA);
    wprep(d2W, 128, 64, 2, -1, 64, 0, wD2cB);
    prep_enc1w<<<5, 256, 0, stream>>>(e1W, We1);

    // --- x features + 2-channel Chebyshev basis (folded: pure P hops) ---
    xcat_init<<<(N * 32 + 255) / 256, 256, 0, stream>>>(x, xcat);
    prop2_kernel<<<ng, 256, 0, stream>>>(rpO, adjO, do_inv, xcat, 0, 2);  // t1o
    prop2_kernel<<<ng, 256, 0, stream>>>(rpO, adjO, do_inv, xcat, 2, 4);  // s2o
    prop2_kernel<<<ng, 256, 0, stream>>>(rpI, adjI, di_inv, xcat, 0, 6);  // t1i
    prop2_kernel<<<ng, 256, 0, stream>>>(rpI, adjI, di_inv, xcat, 6, 8);  // s2i

    auto props = [&](const f16* u) {  // t0..t3 = (t1o, s2o, t1i, s2i) of u
        prop_dual<<<GB, 256, 0, stream>>>(rpO, adjO, do_inv, rpI, adjI, di_inv, u, u, t0, t2);
        prop_dual<<<GB, 256, 0, stream>>>(rpO, adjO, do_inv, rpI, adjI, di_inv, t0, t2, t1, t3);
    };
    const int gg = (N + 63) / 64;

    // enc1
    enc1_kernel<<<GB, 256, 0, stream>>>(xcat, We1, e1b, h1, h1r);
    // enc2 (input h1r, h=0)
    props(h1r);
    mfma_gemm<10, 128, 3><<<gg, 256, 0, stream>>>(h1r, t0, t1, t2, t3, nullptr, wE2,
                                                  nullptr, e2b, e2b + 128, zz);
    combine_h0_kernel<<<GB, 256, 0, stream>>>(zz, h2);
    // dec1 (x=xs, h=h1)
    props(h1);
    mfma_gemm<11, 128, 1><<<gg, 256, 0, stream>>>(h1, t0, t1, t2, t3, xcat, wD1zr,
                                                  nullptr, d1b, d1b + 64, zz);
    mulH_kernel<<<GB, 256, 0, stream>>>(zz, h1, g);
    props(g);
    mfma_gemm<11, 64, 2><<<gg, 256, 0, stream>>>(g, t0, t1, t2, t3, xcat, wD1c,
                                                 nullptr, d1b + 128, d1b + 128, gT);
    combine_relu_kernel<<<GB, 256, 0, stream>>>(zz, gT, h1, h1r);  // h1r := hA
    // dec2 (x=hA, h=h2), K=640 split in halves chained in-place through zz / gT
    props(h1r);
    mfma_gemm<10, 128, 0><<<gg, 256, 0, stream>>>(h1r, t0, t1, t2, t3, nullptr, wD2zrA,
                                                  nullptr, nullptr, nullptr, zz);
    mfma_gemm<10, 64, 0><<<gg, 256, 0, stream>>>(h1r, t0, t1, t2, t3, nullptr, wD2cA,
                                                 nullptr, nullptr, nullptr, gT);
    props(h2);
    mfma_gemm<10, 128, 1><<<gg, 256, 0, stream>>>(h2, t0, t1, t2, t3, nullptr, wD2zrB,
                                                  zz, d2b, d2b + 64, zz);
    mulH_kernel<<<GB, 256, 0, stream>>>(zz, h2, g);
    props(g);
    mfma_gemm<10, 64, 2><<<gg, 256, 0, stream>>>(g, t0, t1, t2, t3, nullptr, wD2cB,
                                                 gT, d2b + 128, d2b + 128, gT);
    final_kernel<<<GB, 256, 0, stream>>>(zz, gT, h2, lW, lb, (float*)d_out);
}

// Round 5
// 1620.368 us; speedup vs baseline: 3.9176x; 1.3620x over previous
//
#include <hip/hip_runtime.h>

#define N_NODES 100000
#define N_EDGES 1600000

typedef _Float16 f16;
typedef _Float16 f16x4 __attribute__((ext_vector_type(4)));
typedef _Float16 f16x8 __attribute__((ext_vector_type(8)));
typedef float f32x4 __attribute__((ext_vector_type(4)));

__device__ __forceinline__ float sigf(float x) { return 1.f / (1.f + __expf(-x)); }

// ---------------- graph preprocessing ----------------

// Count degrees AND remember each edge's slot (atomic return) so fill needs no atomics.
__global__ void count_kernel(const int* __restrict__ src, const int* __restrict__ dst,
                             int* __restrict__ cntO, int* __restrict__ cntI,
                             int* __restrict__ slotO, int* __restrict__ slotI)
{
    int i = blockIdx.x * 256 + threadIdx.x;
    if (i >= N_EDGES) return;
    slotO[i] = atomicAdd(&cntO[dst[i]], 1);   // pout CSR grouped by dst
    slotI[i] = atomicAdd(&cntI[src[i]], 1);   // pin CSR grouped by src
}

// one block per array; block-wide running exclusive scan
__global__ __launch_bounds__(1024) void scan2_kernel(const int* __restrict__ cntA, int* __restrict__ rpA,
                                                     const int* __restrict__ cntB, int* __restrict__ rpB,
                                                     int n)
{
    const int* cnt = blockIdx.x ? cntB : cntA;
    int* rp = blockIdx.x ? rpB : rpA;
    __shared__ int wsum[16];
    __shared__ int carry;
    int tid = threadIdx.x, lane = tid & 63, wid = tid >> 6;
    if (tid == 0) { rp[0] = 0; carry = 0; }
    __syncthreads();
    for (int base = 0; base < n; base += 1024) {
        int idx = base + tid;
        int x = (idx < n) ? cnt[idx] : 0;
        #pragma unroll
        for (int off = 1; off < 64; off <<= 1) {
            int y = __shfl_up(x, off);
            if (lane >= off) x += y;
        }
        if (lane == 63) wsum[wid] = x;
        __syncthreads();
        if (wid == 0 && lane < 16) {
            int y = wsum[lane];
            #pragma unroll
            for (int off = 1; off < 16; off <<= 1) {
                int z = __shfl_up(y, off);
                if (lane >= off) y += z;
            }
            wsum[lane] = y;
        }
        __syncthreads();
        int tot = x + (wid ? wsum[wid - 1] : 0) + carry;
        if (idx < n) rp[idx + 1] = tot;
        __syncthreads();
        if (tid == 1023) carry = tot;
        __syncthreads();
    }
}

// Scatter packed {neighbor, weight_bits} — no atomics (slots precomputed).
__global__ void fill_kernel(const int* __restrict__ src, const int* __restrict__ dst,
                            const float* __restrict__ ew,
                            const int* __restrict__ rpO, const int* __restrict__ rpI,
                            const int* __restrict__ slotO, const int* __restrict__ slotI,
                            int2* __restrict__ adj2O, int2* __restrict__ adj2I)
{
    int i = blockIdx.x * 256 + threadIdx.x;
    if (i >= N_EDGES) return;
    int s = src[i], d = dst[i];
    int wb = __float_as_int(ew[i]);
    int2 eo; eo.x = s; eo.y = wb;
    adj2O[rpO[d] + slotO[i]] = eo;
    int2 ei; ei.x = d; ei.y = wb;
    adj2I[rpI[s] + slotI[i]] = ei;
}

// Compact int2 CSR -> int adjacency, and compute inverse degrees in the same sweep.
__global__ void finalize_kernel(const int* __restrict__ rpO, const int2* __restrict__ adj2O,
                                int* __restrict__ adjO, float* __restrict__ di_inv,
                                const int* __restrict__ rpI, const int2* __restrict__ adj2I,
                                int* __restrict__ adjI, float* __restrict__ do_inv)
{
    int n = blockIdx.x * 256 + threadIdx.x;
    if (n >= N_NODES) return;
    float s = 0.f;
    for (int e = rpO[n]; e < rpO[n + 1]; ++e) {
        int2 v = adj2O[e];
        adjO[e] = v.x;
        s += __int_as_float(v.y);
    }
    di_inv[n] = (s > 0.f) ? 1.f / s : 0.f;
    float t = 0.f;
    for (int e = rpI[n]; e < rpI[n + 1]; ++e) {
        int2 v = adj2I[e];
        adjI[e] = v.x;
        t += __int_as_float(v.y);
    }
    do_inv[n] = (t > 0.f) ? 1.f / t : 0.f;
}

// ---------------- weight preprocessing (Chebyshev-folded) ----------------
// Parts: p0=u (W00+W10-W02-W12), p1=t1o (W01), p2=s2o=P_o(t1o) (2*W02),
//        p3=t1i (W11), p4=s2i (2*W12).
__global__ void prep_w(const float* __restrict__ W, int C, int rowBase,
                       int gLo, int gHi, int COLS, int XSTEP, f16* __restrict__ outw)
{
    int total = (10 + XSTEP) * COLS * 32;
    int idx = blockIdx.x * 256 + threadIdx.x;
    if (idx >= total) return;
    int k32 = idx & 31;
    int c = (idx >> 5) % COLS;
    int s = (idx >> 5) / COLS;
    int g = (c < 64 || gHi < 0) ? gLo : gHi;
    int col = (c >= 64) ? c - 64 : c;
    int p, r;
    if (s < 10) { p = s >> 1; r = rowBase + ((s & 1) << 5) + k32; }
    else {
        if (k32 < 10) { p = k32 >> 1; r = k32 & 1; }
        else { outw[idx] = (f16)0.f; return; }
    }
    auto wv = [&](int d, int k) {
        return W[((((size_t)(g * 2 + d) * 3 + k) * C + r) << 6) + col];
    };
    float val;
    if (p == 0)      val = wv(0, 0) + wv(1, 0) - wv(0, 2) - wv(1, 2);
    else if (p == 1) val = wv(0, 1);
    else if (p == 2) val = 2.f * wv(0, 2);
    else if (p == 3) val = wv(1, 1);
    else             val = 2.f * wv(1, 2);
    outw[idx] = (f16)val;
}

// enc1 weights fp32 [10][128]: cols 0-63 gate z(0), 64-127 gate h(2); C=66, x rows 0..1
__global__ void prep_enc1w(const float* __restrict__ W, float* __restrict__ outw)
{
    int idx = blockIdx.x * 256 + threadIdx.x;
    if (idx >= 1280) return;
    int c = idx & 127, k = idx >> 7;
    int g = (c < 64) ? 0 : 2, col = c & 63;
    int p = k >> 1, r = k & 1;
    const int C = 66;
    auto wv = [&](int d, int kk) {
        return W[((((size_t)(g * 2 + d) * 3 + kk) * C + r) << 6) + col];
    };
    float val;
    if (p == 0)      val = wv(0, 0) + wv(1, 0) - wv(0, 2) - wv(1, 2);
    else if (p == 1) val = wv(0, 1);
    else if (p == 2) val = 2.f * wv(0, 2);
    else if (p == 3) val = wv(1, 1);
    else             val = 2.f * wv(1, 2);
    outw[idx] = val;
}

// xcat fp16 [N][32]: cols 0-1 = xs, 2-9 = (t1o, s2o, t1i, s2i), 10-31 zero
__global__ void xcat_init(const float* __restrict__ x, f16* __restrict__ xcat)
{
    int i = blockIdx.x * 256 + threadIdx.x;
    if (i >= N_NODES * 32) return;
    int n = i >> 5, c = i & 31;
    float v = (c < 2) ? x[(size_t)n * 24 + c] : 0.f;  // x[:, :, 0, :] of (4,25000,12,2)
    xcat[i] = (f16)v;
}

// 2-channel pure propagation inside xcat; write cols disjoint from read cols
__global__ void prop2_kernel(const int* __restrict__ rp, const int* __restrict__ adj,
                             const float* __restrict__ scale, f16* __restrict__ xcat,
                             int cin, int cout)
{
    int n = blockIdx.x * 256 + threadIdx.x;
    if (n >= N_NODES) return;
    int beg = rp[n], end = rp[n + 1];
    float a0 = 0.f, a1 = 0.f;
    for (int e = beg; e < end; ++e) {
        int s = adj[e];
        float w = scale[s];
        a0 += w * (float)xcat[((size_t)s << 5) + cin];
        a1 += w * (float)xcat[((size_t)s << 5) + cin + 1];
    }
    xcat[((size_t)n << 5) + cout] = (f16)a0;
    xcat[((size_t)n << 5) + cout + 1] = (f16)a1;
}

// ---------------- 64-ch propagation: 16 lanes/node, f16x4 loads, dir = blockIdx.y ----
__global__ __launch_bounds__(256) void prop16(
    const int* __restrict__ rpA, const int* __restrict__ adjA, const float* __restrict__ scA,
    const f16* __restrict__ uA, f16* __restrict__ outA,
    const int* __restrict__ rpB, const int* __restrict__ adjB, const float* __restrict__ scB,
    const f16* __restrict__ uB, f16* __restrict__ outB)
{
    const int* RP; const int* ADJ; const float* SC; const f16* U; f16* OUT;
    if (blockIdx.y == 0) { RP = rpA; ADJ = adjA; SC = scA; U = uA; OUT = outA; }
    else                 { RP = rpB; ADJ = adjB; SC = scB; U = uB; OUT = outB; }
    int tid = threadIdx.x;
    int node = blockIdx.x * 16 + (tid >> 4);   // 4 waves * 4 nodes each
    int l = tid & 15;                           // lane-within-node: channels l*4..l*4+3
    if (node >= N_NODES) return;
    int b = RP[node], e = RP[node + 1];
    float a0 = 0.f, a1 = 0.f, a2 = 0.f, a3 = 0.f;
    float b0 = 0.f, b1 = 0.f, b2 = 0.f, b3 = 0.f;
    int i = b;
    for (; i + 1 < e; i += 2) {
        int s0 = ADJ[i], s1 = ADJ[i + 1];
        float w0 = SC[s0], w1 = SC[s1];
        f16x4 u0 = *(const f16x4*)(U + (((size_t)s0 << 6) + (l << 2)));
        f16x4 u1 = *(const f16x4*)(U + (((size_t)s1 << 6) + (l << 2)));
        a0 += w0 * (float)u0[0]; a1 += w0 * (float)u0[1];
        a2 += w0 * (float)u0[2]; a3 += w0 * (float)u0[3];
        b0 += w1 * (float)u1[0]; b1 += w1 * (float)u1[1];
        b2 += w1 * (float)u1[2]; b3 += w1 * (float)u1[3];
    }
    if (i < e) {
        int s = ADJ[i];
        float w = SC[s];
        f16x4 u0 = *(const f16x4*)(U + (((size_t)s << 6) + (l << 2)));
        a0 += w * (float)u0[0]; a1 += w * (float)u0[1];
        a2 += w * (float)u0[2]; a3 += w * (float)u0[3];
    }
    f16x4 r;
    r[0] = (f16)(a0 + b0); r[1] = (f16)(a1 + b1);
    r[2] = (f16)(a2 + b2); r[3] = (f16)(a3 + b3);
    *(f16x4*)(OUT + (((size_t)node << 6) + (l << 2))) = r;
}

// ---------------- MFMA GEMM over virtually-concatenated parts ----------------
// out[N,COLS-ish] = ACT( sum_steps A_s[N,32] @ Wstep_s[32,COLS] + addX + bias )
// ACT: 0 none, 1 sigmoid, 2 tanh,
//      4 fused GRU-h0 (COLS=128: z=sig(lo), t=tanh(hi), out[N,64] = (1-z)*t),
//      5 fused z|R*h  (COLS=128: out[N,64]=sig(lo)=z, out2[N,64]=sig(hi)*hmul)
template <int STEPS, int COLS, int ACT>
__global__ __launch_bounds__(256) void mfma_gemm(
    const f16* __restrict__ p0, const f16* __restrict__ p1, const f16* __restrict__ p2,
    const f16* __restrict__ p3, const f16* __restrict__ p4, const f16* __restrict__ xcat,
    const f16* __restrict__ wstep, const f16* __restrict__ addX,
    const float* __restrict__ biasLo, const float* __restrict__ biasHi,
    f16* __restrict__ out, const f16* __restrict__ hmul, f16* __restrict__ out2)
{
    __shared__ f16 As[64][40];     // [row][k], pad 40 halves
    __shared__ f16 Ws[COLS][40];   // [col][k]
    const int row0 = blockIdx.x * 64;
    const int tid = threadIdx.x;
    const int wave = tid >> 6, lane = tid & 63;
    const int lr = lane & 15, lk = lane >> 4;
    const int ka = lk << 3;

    constexpr int RT = (COLS == 128) ? 4 : 2;
    f32x4 acc[RT][2] = {};

    const f16* parts[5] = { p0, p1, p2, p3, p4 };

    #pragma unroll
    for (int s = 0; s < STEPS; ++s) {
        __syncthreads();
        {   // stage A tile: 64 rows x 32 halves
            int r = tid >> 2, seg = tid & 3;
            int grow = row0 + r;
            const f16* srcp = (s < 10)
                ? parts[s >> 1] + (((size_t)grow << 6) + ((s & 1) << 5) + (seg << 3))
                : xcat + (((size_t)grow << 5) + (seg << 3));
            int4 v = (grow < N_NODES) ? *(const int4*)srcp : make_int4(0, 0, 0, 0);
            *(int4*)&As[r][seg << 3] = v;
        }
        {   // stage W tile: COLS x 32 halves
            for (int q = tid; q < COLS * 4; q += 256) {
                int c = q >> 2, seg = q & 3;
                *(int4*)&Ws[c][seg << 3] =
                    *(const int4*)(wstep + (((size_t)(s * COLS + c) << 5) + (seg << 3)));
            }
        }
        __syncthreads();
        if (COLS == 128) {
            f16x8 b0 = *(const f16x8*)&Ws[wave * 32 + lr][ka];
            f16x8 b1 = *(const f16x8*)&Ws[wave * 32 + 16 + lr][ka];
            #pragma unroll
            for (int rt = 0; rt < RT; ++rt) {
                f16x8 a = *(const f16x8*)&As[rt * 16 + lr][ka];
                acc[rt][0] = __builtin_amdgcn_mfma_f32_16x16x32_f16(a, b0, acc[rt][0], 0, 0, 0);
                acc[rt][1] = __builtin_amdgcn_mfma_f32_16x16x32_f16(a, b1, acc[rt][1], 0, 0, 0);
            }
        } else {
            f16x8 b0 = *(const f16x8*)&Ws[(wave & 1) * 32 + lr][ka];
            f16x8 b1 = *(const f16x8*)&Ws[(wave & 1) * 32 + 16 + lr][ka];
            #pragma unroll
            for (int rt = 0; rt < RT; ++rt) {
                f16x8 a = *(const f16x8*)&As[(wave >> 1) * 32 + rt * 16 + lr][ka];
                acc[rt][0] = __builtin_amdgcn_mfma_f32_16x16x32_f16(a, b0, acc[rt][0], 0, 0, 0);
                acc[rt][1] = __builtin_amdgcn_mfma_f32_16x16x32_f16(a, b1, acc[rt][1], 0, 0, 0);
            }
        }
    }
    // D layout: col=lane&15 (+16*ct+32*wavepart), row=(lane>>4)*4+reg
    if constexpr (ACT == 4) {
        __shared__ float zbuf[64][65];
        float treg[RT][2][4];
        #pragma unroll
        for (int rt = 0; rt < RT; ++rt)
            #pragma unroll
            for (int ct = 0; ct < 2; ++ct) {
                int col = wave * 32 + ct * 16 + lr;
                #pragma unroll
                for (int j = 0; j < 4; ++j) {
                    int r = rt * 16 + lk * 4 + j;
                    float v = acc[rt][ct][j] + ((col < 64) ? biasLo[col] : biasHi[col - 64]);
                    if (col < 64) zbuf[r][col] = sigf(v);
                    else          treg[rt][ct][j] = tanhf(v);
                }
            }
        __syncthreads();
        #pragma unroll
        for (int rt = 0; rt < RT; ++rt)
            #pragma unroll
            for (int ct = 0; ct < 2; ++ct) {
                int col = wave * 32 + ct * 16 + lr;
                if (col < 64) continue;
                #pragma unroll
                for (int j = 0; j < 4; ++j) {
                    int r = rt * 16 + lk * 4 + j;
                    int grow = row0 + r;
                    if (grow >= N_NODES) continue;
                    float h = (1.f - zbuf[r][col - 64]) * treg[rt][ct][j];
                    out[((size_t)grow << 6) + (col - 64)] = (f16)h;
                }
            }
    } else if constexpr (ACT == 5) {
        #pragma unroll
        for (int rt = 0; rt < RT; ++rt)
            #pragma unroll
            for (int ct = 0; ct < 2; ++ct) {
                int col = wave * 32 + ct * 16 + lr;
                #pragma unroll
                for (int j = 0; j < 4; ++j) {
                    int grow = row0 + rt * 16 + lk * 4 + j;
                    if (grow >= N_NODES) continue;
                    float v = acc[rt][ct][j];
                    if (addX) v += (float)addX[((size_t)grow << 7) + col];
                    v += (col < 64) ? biasLo[col] : biasHi[col - 64];
                    float sg = sigf(v);
                    if (col < 64)
                        out[((size_t)grow << 6) + col] = (f16)sg;   // z gate
                    else
                        out2[((size_t)grow << 6) + (col - 64)] =    // g = R*h
                            (f16)(sg * (float)hmul[((size_t)grow << 6) + (col - 64)]);
                }
            }
    } else {
        #pragma unroll
        for (int rt = 0; rt < RT; ++rt) {
            int rbase = (COLS == 128) ? rt * 16 : (wave >> 1) * 32 + rt * 16;
            #pragma unroll
            for (int ct = 0; ct < 2; ++ct) {
                int col = ((COLS == 128) ? wave * 32 : (wave & 1) * 32) + ct * 16 + lr;
                #pragma unroll
                for (int j = 0; j < 4; ++j) {
                    int grow = row0 + rbase + lk * 4 + j;
                    if (grow >= N_NODES) continue;
                    float v = acc[rt][ct][j];
                    if (addX)   v += (float)addX[(size_t)grow * COLS + col];
                    if (biasLo) v += (col < 64) ? biasLo[col] : biasHi[col - 64];
                    if (ACT == 1)      v = sigf(v);
                    else if (ACT == 2) v = tanhf(v);
                    out[(size_t)grow * COLS + col] = (f16)v;
                }
            }
        }
    }
}

// ---------------- fused enc1 (K=10 VALU GEMM + GRU combine) ----------------
__global__ __launch_bounds__(256) void enc1_kernel(const f16* __restrict__ xcat,
                                                   const float* __restrict__ We1,
                                                   const float* __restrict__ b,
                                                   f16* __restrict__ h1, f16* __restrict__ h1r)
{
    int node = (blockIdx.x << 2) + (threadIdx.x >> 6);
    int lane = threadIdx.x & 63;
    float az = b[lane], at = b[128 + lane];
    #pragma unroll
    for (int k = 0; k < 10; ++k) {
        float xv = (float)xcat[((size_t)node << 5) + k];
        az += xv * We1[k * 128 + lane];
        at += xv * We1[k * 128 + 64 + lane];
    }
    float z = sigf(az), t = tanhf(at);
    float h = (1.f - z) * t;
    size_t o = ((size_t)node << 6) + lane;
    h1[o] = (f16)h;
    h1r[o] = (f16)fmaxf(h, 0.f);
}

// ---------------- elementwise glue ----------------

// h1r := relu(z*hprev + (1-z)*gT), z stride 64
__global__ void combine_relu_kernel(const f16* __restrict__ zb, const f16* __restrict__ gT,
                                    const f16* __restrict__ hprev, f16* __restrict__ hA)
{
    int i = blockIdx.x * 256 + threadIdx.x;
    float z = (float)zb[i];
    float v = z * (float)hprev[i] + (1.f - z) * (float)gT[i];
    hA[i] = (f16)fmaxf(v, 0.f);
}

__global__ __launch_bounds__(256) void final_kernel(const f16* __restrict__ zb, const f16* __restrict__ gT,
                                                    const f16* __restrict__ h2,
                                                    const float* __restrict__ lW, const float* __restrict__ lb,
                                                    float* __restrict__ out)
{
    int node = (blockIdx.x << 2) + (threadIdx.x >> 6);
    int lane = threadIdx.x & 63;
    size_t i = ((size_t)node << 6) + lane;
    float z = (float)zb[i];
    float d = z * (float)h2[i] + (1.f - z) * (float)gT[i];
    float s0 = d * lW[lane * 2];
    float s1 = d * lW[lane * 2 + 1];
    #pragma unroll
    for (int off = 32; off > 0; off >>= 1) {
        s0 += __shfl_down(s0, off);
        s1 += __shfl_down(s1, off);
    }
    if (lane == 0) {
        out[node * 2]     = s0 + lb[0];
        out[node * 2 + 1] = s1 + lb[1];
    }
}

// ---------------- driver ----------------

extern "C" void kernel_launch(void* const* d_in, const int* in_sizes, int n_in,
                              void* d_out, int out_size, void* d_ws, size_t ws_size,
                              hipStream_t stream)
{
    (void)in_sizes; (void)n_in; (void)out_size;
    const float* x   = (const float*)d_in[0];
    const int*  eidx = (const int*)d_in[1];
    const float* ew  = (const float*)d_in[2];
    const float* e1W = (const float*)d_in[3];
    const float* e1b = (const float*)d_in[4];
    const float* e2W = (const float*)d_in[5];
    const float* e2b = (const float*)d_in[6];
    const float* d1W = (const float*)d_in[7];
    const float* d1b = (const float*)d_in[8];
    const float* d2W = (const float*)d_in[9];
    const float* d2b = (const float*)d_in[10];
    const float* lW  = (const float*)d_in[11];
    const float* lb  = (const float*)d_in[12];
    const int* src = eidx;
    const int* dst = eidx + N_EDGES;
    const int N = N_NODES, E = N_EDGES;

    char* p = (char*)d_ws;
    auto carve = [&](size_t bytes) { char* r = p; p += (bytes + 255) & ~(size_t)255; return r; };
    int*   cntO  = (int*)carve((size_t)2 * N * 4);
    int*   cntI  = cntO + N;
    int*   rpO   = (int*)carve((size_t)(N + 1) * 4);
    int*   rpI   = (int*)carve((size_t)(N + 1) * 4);
    int*   slotO = (int*)carve((size_t)E * 4);   // later reused as adjO
    int*   slotI = (int*)carve((size_t)E * 4);   // later reused as adjI
    int2*  adj2O = (int2*)carve((size_t)E * 8);
    int2*  adj2I = (int2*)carve((size_t)E * 8);
    float* do_inv = (float*)carve((size_t)N * 4);
    float* di_inv = (float*)carve((size_t)N * 4);
    f16*   xcat = (f16*)carve((size_t)N * 32 * 2);
    size_t NH = (size_t)N * 64 * 2;
    f16* h1  = (f16*)carve(NH);
    f16* h1r = (f16*)carve(NH);   // reused as hA after enc2
    f16* h2  = (f16*)carve(NH);
    f16* g   = (f16*)carve(NH);
    f16* gT  = (f16*)carve(NH);
    f16* t0  = (f16*)carve(NH);   // t1o
    f16* t1  = (f16*)carve(NH);   // s2o
    f16* t2  = (f16*)carve(NH);   // t1i
    f16* t3  = (f16*)carve(NH);   // s2i
    f16* zb  = (f16*)carve(NH);                      // z gate [N,64]
    f16* zz128 = (f16*)carve((size_t)N * 128 * 2);   // dec2 partial [N,128]
    f16* wE2   = (f16*)carve((size_t)10 * 128 * 32 * 2);
    f16* wD1zr = (f16*)carve((size_t)11 * 128 * 32 * 2);
    f16* wD1c  = (f16*)carve((size_t)11 * 64 * 32 * 2);
    f16* wD2zrA = (f16*)carve((size_t)10 * 128 * 32 * 2);
    f16* wD2zrB = (f16*)carve((size_t)10 * 128 * 32 * 2);
    f16* wD2cA  = (f16*)carve((size_t)10 * 64 * 32 * 2);
    f16* wD2cB  = (f16*)carve((size_t)10 * 64 * 32 * 2);
    float* We1  = (float*)carve((size_t)1280 * 4);

    size_t needed = (size_t)(p - (char*)d_ws);
    if (needed > ws_size) return;   // clean failure (diagnosable) instead of fault

    const int eg = (E + 255) / 256;
    const int ng = (N + 255) / 256;
    const int GB = 25000;           // N*64/256 elementwise grid; N/4 node-wave grid

    // --- graph prep ---
    hipMemsetAsync(cntO, 0, (size_t)2 * N * 4, stream);
    count_kernel<<<eg, 256, 0, stream>>>(src, dst, cntO, cntI, slotO, slotI);
    scan2_kernel<<<2, 1024, 0, stream>>>(cntO, rpO, cntI, rpI, N);
    fill_kernel<<<eg, 256, 0, stream>>>(src, dst, ew, rpO, rpI, slotO, slotI, adj2O, adj2I);
    int* adjO = slotO;  // slot arrays dead after fill; reuse as compact adjacency
    int* adjI = slotI;
    finalize_kernel<<<ng, 256, 0, stream>>>(rpO, adj2O, adjO, di_inv, rpI, adj2I, adjI, do_inv);

    // --- weight prep ---
    auto wprep = [&](const float* W, int C, int rowBase, int gLo, int gHi, int COLS, int XS, f16* o) {
        int total = (10 + XS) * COLS * 32;
        prep_w<<<(total + 255) / 256, 256, 0, stream>>>(W, C, rowBase, gLo, gHi, COLS, XS, o);
    };
    wprep(e2W, 128, 0,  0, 2, 128, 0, wE2);
    wprep(d1W, 66,  2,  0, 1, 128, 1, wD1zr);
    wprep(d1W, 66,  2,  2, -1, 64, 1, wD1c);
    wprep(d2W, 128, 0,  0, 1, 128, 0, wD2zrA);
    wprep(d2W, 128, 64, 0, 1, 128, 0, wD2zrB);
    wprep(d2W, 128, 0,  2, -1, 64, 0, wD2cA);
    wprep(d2W, 128, 64, 2, -1, 64, 0, wD2cB);
    prep_enc1w<<<5, 256, 0, stream>>>(e1W, We1);

    // --- x features + 2-channel Chebyshev basis (folded: pure P hops) ---
    xcat_init<<<(N * 32 + 255) / 256, 256, 0, stream>>>(x, xcat);
    prop2_kernel<<<ng, 256, 0, stream>>>(rpO, adjO, do_inv, xcat, 0, 2);  // t1o
    prop2_kernel<<<ng, 256, 0, stream>>>(rpO, adjO, do_inv, xcat, 2, 4);  // s2o
    prop2_kernel<<<ng, 256, 0, stream>>>(rpI, adjI, di_inv, xcat, 0, 6);  // t1i
    prop2_kernel<<<ng, 256, 0, stream>>>(rpI, adjI, di_inv, xcat, 6, 8);  // s2i

    const dim3 pg((N + 15) / 16, 2);
    auto props = [&](const f16* u) {  // t0..t3 = (t1o, s2o, t1i, s2i) of u
        prop16<<<pg, 256, 0, stream>>>(rpO, adjO, do_inv, u, t0,
                                       rpI, adjI, di_inv, u, t2);
        prop16<<<pg, 256, 0, stream>>>(rpO, adjO, do_inv, t0, t1,
                                       rpI, adjI, di_inv, t2, t3);
    };
    const int gg = (N + 63) / 64;

    // enc1
    enc1_kernel<<<GB, 256, 0, stream>>>(xcat, We1, e1b, h1, h1r);
    // enc2 (input h1r, h=0): fused GRU-h0 epilogue writes h2 directly
    props(h1r);
    mfma_gemm<10, 128, 4><<<gg, 256, 0, stream>>>(h1r, t0, t1, t2, t3, nullptr, wE2,
                                                  nullptr, e2b, e2b + 128, h2, nullptr, nullptr);
    // dec1 (x=xs, h=h1): fused z|R*h epilogue
    props(h1);
    mfma_gemm<11, 128, 5><<<gg, 256, 0, stream>>>(h1, t0, t1, t2, t3, xcat, wD1zr,
                                                  nullptr, d1b, d1b + 64, zb, h1, g);
    props(g);
    mfma_gemm<11, 64, 2><<<gg, 256, 0, stream>>>(g, t0, t1, t2, t3, xcat, wD1c,
                                                 nullptr, d1b + 128, d1b + 128, gT, nullptr, nullptr);
    combine_relu_kernel<<<GB, 256, 0, stream>>>(zb, gT, h1, h1r);  // h1r := hA
    // dec2 (x=hA, h=h2): K=640 split in halves; partials chained through zz128 / gT
    props(h1r);
    mfma_gemm<10, 128, 0><<<gg, 256, 0, stream>>>(h1r, t0, t1, t2, t3, nullptr, wD2zrA,
                                                  nullptr, nullptr, nullptr, zz128, nullptr, nullptr);
    mfma_gemm<10, 64, 0><<<gg, 256, 0, stream>>>(h1r, t0, t1, t2, t3, nullptr, wD2cA,
                                                 nullptr, nullptr, nullptr, gT, nullptr, nullptr);
    props(h2);
    mfma_gemm<10, 128, 5><<<gg, 256, 0, stream>>>(h2, t0, t1, t2, t3, nullptr, wD2zrB,
                                                  zz128, d2b, d2b + 64, zb, h2, g);
    props(g);
    mfma_gemm<10, 64, 2><<<gg, 256, 0, stream>>>(g, t0, t1, t2, t3, nullptr, wD2cB,
                                                 gT, d2b + 128, d2b + 128, gT, nullptr, nullptr);
    final_kernel<<<GB, 256, 0, stream>>>(zb, gT, h2, lW, lb, (float*)d_out);
}

// Round 6
// 1479.916 us; speedup vs baseline: 4.2894x; 1.0949x over previous
//
#include <hip/hip_runtime.h>

#define N_NODES 100000
#define N_EDGES 1600000

typedef _Float16 f16;
typedef _Float16 f16x4 __attribute__((ext_vector_type(4)));
typedef _Float16 f16x8 __attribute__((ext_vector_type(8)));
typedef float f32x4 __attribute__((ext_vector_type(4)));

__device__ __forceinline__ float sigf(float x) { return 1.f / (1.f + __expf(-x)); }

// ---------------- graph preprocessing ----------------

// Count degrees AND remember each edge's slot (atomic return) so fill needs no atomics.
__global__ void count_kernel(const int* __restrict__ src, const int* __restrict__ dst,
                             int* __restrict__ cntO, int* __restrict__ cntI,
                             int* __restrict__ slotO, int* __restrict__ slotI)
{
    int i = blockIdx.x * 256 + threadIdx.x;
    if (i >= N_EDGES) return;
    slotO[i] = atomicAdd(&cntO[dst[i]], 1);   // pout CSR grouped by dst
    slotI[i] = atomicAdd(&cntI[src[i]], 1);   // pin CSR grouped by src
}

// one block per array; block-wide running exclusive scan
__global__ __launch_bounds__(1024) void scan2_kernel(const int* __restrict__ cntA, int* __restrict__ rpA,
                                                     const int* __restrict__ cntB, int* __restrict__ rpB,
                                                     int n)
{
    const int* cnt = blockIdx.x ? cntB : cntA;
    int* rp = blockIdx.x ? rpB : rpA;
    __shared__ int wsum[16];
    __shared__ int carry;
    int tid = threadIdx.x, lane = tid & 63, wid = tid >> 6;
    if (tid == 0) { rp[0] = 0; carry = 0; }
    __syncthreads();
    for (int base = 0; base < n; base += 1024) {
        int idx = base + tid;
        int x = (idx < n) ? cnt[idx] : 0;
        #pragma unroll
        for (int off = 1; off < 64; off <<= 1) {
            int y = __shfl_up(x, off);
            if (lane >= off) x += y;
        }
        if (lane == 63) wsum[wid] = x;
        __syncthreads();
        if (wid == 0 && lane < 16) {
            int y = wsum[lane];
            #pragma unroll
            for (int off = 1; off < 16; off <<= 1) {
                int z = __shfl_up(y, off);
                if (lane >= off) y += z;
            }
            wsum[lane] = y;
        }
        __syncthreads();
        int tot = x + (wid ? wsum[wid - 1] : 0) + carry;
        if (idx < n) rp[idx + 1] = tot;
        __syncthreads();
        if (tid == 1023) carry = tot;
        __syncthreads();
    }
}

// Scatter packed {neighbor, weight_bits} — no atomics (slots precomputed).
__global__ void fill_kernel(const int* __restrict__ src, const int* __restrict__ dst,
                            const float* __restrict__ ew,
                            const int* __restrict__ rpO, const int* __restrict__ rpI,
                            const int* __restrict__ slotO, const int* __restrict__ slotI,
                            int2* __restrict__ adj2O, int2* __restrict__ adj2I)
{
    int i = blockIdx.x * 256 + threadIdx.x;
    if (i >= N_EDGES) return;
    int s = src[i], d = dst[i];
    int wb = __float_as_int(ew[i]);
    int2 eo; eo.x = s; eo.y = wb;
    adj2O[rpO[d] + slotO[i]] = eo;
    int2 ei; ei.x = d; ei.y = wb;
    adj2I[rpI[s] + slotI[i]] = ei;
}

// Compact int2 CSR -> int adjacency, and compute inverse degrees in the same sweep.
__global__ void finalize_kernel(const int* __restrict__ rpO, const int2* __restrict__ adj2O,
                                int* __restrict__ adjO, float* __restrict__ di_inv,
                                const int* __restrict__ rpI, const int2* __restrict__ adj2I,
                                int* __restrict__ adjI, float* __restrict__ do_inv)
{
    int n = blockIdx.x * 256 + threadIdx.x;
    if (n >= N_NODES) return;
    float s = 0.f;
    for (int e = rpO[n]; e < rpO[n + 1]; ++e) {
        int2 v = adj2O[e];
        adjO[e] = v.x;
        s += __int_as_float(v.y);
    }
    di_inv[n] = (s > 0.f) ? 1.f / s : 0.f;
    float t = 0.f;
    for (int e = rpI[n]; e < rpI[n + 1]; ++e) {
        int2 v = adj2I[e];
        adjI[e] = v.x;
        t += __int_as_float(v.y);
    }
    do_inv[n] = (t > 0.f) ? 1.f / t : 0.f;
}

// ---------------- weight preprocessing (Chebyshev-folded) ----------------
// Parts: p0=u (W00+W10-W02-W12), p1=t1o (W01), p2=s2o=P_o(t1o) (2*W02),
//        p3=t1i (W11), p4=s2i (2*W12).
__global__ void prep_w(const float* __restrict__ W, int C, int rowBase,
                       int gLo, int gHi, int COLS, int XSTEP, f16* __restrict__ outw)
{
    int total = (10 + XSTEP) * COLS * 32;
    int idx = blockIdx.x * 256 + threadIdx.x;
    if (idx >= total) return;
    int k32 = idx & 31;
    int c = (idx >> 5) % COLS;
    int s = (idx >> 5) / COLS;
    int g = (c < 64 || gHi < 0) ? gLo : gHi;
    int col = (c >= 64) ? c - 64 : c;
    int p, r;
    if (s < 10) { p = s >> 1; r = rowBase + ((s & 1) << 5) + k32; }
    else {
        if (k32 < 10) { p = k32 >> 1; r = k32 & 1; }
        else { outw[idx] = (f16)0.f; return; }
    }
    auto wv = [&](int d, int k) {
        return W[((((size_t)(g * 2 + d) * 3 + k) * C + r) << 6) + col];
    };
    float val;
    if (p == 0)      val = wv(0, 0) + wv(1, 0) - wv(0, 2) - wv(1, 2);
    else if (p == 1) val = wv(0, 1);
    else if (p == 2) val = 2.f * wv(0, 2);
    else if (p == 3) val = wv(1, 1);
    else             val = 2.f * wv(1, 2);
    outw[idx] = (f16)val;
}

// enc1 weights fp32 [10][128]: cols 0-63 gate z(0), 64-127 gate h(2); C=66, x rows 0..1
__global__ void prep_enc1w(const float* __restrict__ W, float* __restrict__ outw)
{
    int idx = blockIdx.x * 256 + threadIdx.x;
    if (idx >= 1280) return;
    int c = idx & 127, k = idx >> 7;
    int g = (c < 64) ? 0 : 2, col = c & 63;
    int p = k >> 1, r = k & 1;
    const int C = 66;
    auto wv = [&](int d, int kk) {
        return W[((((size_t)(g * 2 + d) * 3 + kk) * C + r) << 6) + col];
    };
    float val;
    if (p == 0)      val = wv(0, 0) + wv(1, 0) - wv(0, 2) - wv(1, 2);
    else if (p == 1) val = wv(0, 1);
    else if (p == 2) val = 2.f * wv(0, 2);
    else if (p == 3) val = wv(1, 1);
    else             val = 2.f * wv(1, 2);
    outw[idx] = val;
}

// xcat fp16 [N][32]: cols 0-1 = xs, 2-9 = (t1o, s2o, t1i, s2i), 10-31 zero
__global__ void xcat_init(const float* __restrict__ x, f16* __restrict__ xcat)
{
    int i = blockIdx.x * 256 + threadIdx.x;
    if (i >= N_NODES * 32) return;
    int n = i >> 5, c = i & 31;
    float v = (c < 2) ? x[(size_t)n * 24 + c] : 0.f;  // x[:, :, 0, :] of (4,25000,12,2)
    xcat[i] = (f16)v;
}

// 2-channel pure propagation inside xcat; write cols disjoint from read cols
__global__ void prop2_kernel(const int* __restrict__ rp, const int* __restrict__ adj,
                             const float* __restrict__ scale, f16* __restrict__ xcat,
                             int cin, int cout)
{
    int n = blockIdx.x * 256 + threadIdx.x;
    if (n >= N_NODES) return;
    int beg = rp[n], end = rp[n + 1];
    float a0 = 0.f, a1 = 0.f;
    for (int e = beg; e < end; ++e) {
        int s = adj[e];
        float w = scale[s];
        a0 += w * (float)xcat[((size_t)s << 5) + cin];
        a1 += w * (float)xcat[((size_t)s << 5) + cin + 1];
    }
    xcat[((size_t)n << 5) + cout] = (f16)a0;
    xcat[((size_t)n << 5) + cout + 1] = (f16)a1;
}

// ---------------- 64-ch propagation: 8 lanes/node, f16x8 loads, dir = blockIdx.y ----
__global__ __launch_bounds__(256) void prop8(
    const int* __restrict__ rpA, const int* __restrict__ adjA, const float* __restrict__ scA,
    const f16* __restrict__ uA, f16* __restrict__ outA,
    const int* __restrict__ rpB, const int* __restrict__ adjB, const float* __restrict__ scB,
    const f16* __restrict__ uB, f16* __restrict__ outB)
{
    const int* RP; const int* ADJ; const float* SC; const f16* U; f16* OUT;
    if (blockIdx.y == 0) { RP = rpA; ADJ = adjA; SC = scA; U = uA; OUT = outA; }
    else                 { RP = rpB; ADJ = adjB; SC = scB; U = uB; OUT = outB; }
    int tid = threadIdx.x;
    int node = blockIdx.x * 32 + (tid >> 3);   // 4 waves * 8 nodes each
    int l = tid & 7;                            // channel octet: channels l*8..l*8+7
    if (node >= N_NODES) return;
    int b = RP[node], e = RP[node + 1];
    float a0 = 0.f, a1 = 0.f, a2 = 0.f, a3 = 0.f;
    float a4 = 0.f, a5 = 0.f, a6 = 0.f, a7 = 0.f;
    float c0 = 0.f, c1 = 0.f, c2 = 0.f, c3 = 0.f;
    float c4 = 0.f, c5 = 0.f, c6 = 0.f, c7 = 0.f;
    int i = b;
    for (; i + 1 < e; i += 2) {
        int s0 = ADJ[i], s1 = ADJ[i + 1];
        float w0 = SC[s0], w1 = SC[s1];
        f16x8 u0 = *(const f16x8*)(U + (((size_t)s0 << 6) + (l << 3)));
        f16x8 u1 = *(const f16x8*)(U + (((size_t)s1 << 6) + (l << 3)));
        a0 += w0 * (float)u0[0]; a1 += w0 * (float)u0[1];
        a2 += w0 * (float)u0[2]; a3 += w0 * (float)u0[3];
        a4 += w0 * (float)u0[4]; a5 += w0 * (float)u0[5];
        a6 += w0 * (float)u0[6]; a7 += w0 * (float)u0[7];
        c0 += w1 * (float)u1[0]; c1 += w1 * (float)u1[1];
        c2 += w1 * (float)u1[2]; c3 += w1 * (float)u1[3];
        c4 += w1 * (float)u1[4]; c5 += w1 * (float)u1[5];
        c6 += w1 * (float)u1[6]; c7 += w1 * (float)u1[7];
    }
    if (i < e) {
        int s = ADJ[i];
        float w = SC[s];
        f16x8 u0 = *(const f16x8*)(U + (((size_t)s << 6) + (l << 3)));
        a0 += w * (float)u0[0]; a1 += w * (float)u0[1];
        a2 += w * (float)u0[2]; a3 += w * (float)u0[3];
        a4 += w * (float)u0[4]; a5 += w * (float)u0[5];
        a6 += w * (float)u0[6]; a7 += w * (float)u0[7];
    }
    f16x8 r;
    r[0] = (f16)(a0 + c0); r[1] = (f16)(a1 + c1);
    r[2] = (f16)(a2 + c2); r[3] = (f16)(a3 + c3);
    r[4] = (f16)(a4 + c4); r[5] = (f16)(a5 + c5);
    r[6] = (f16)(a6 + c6); r[7] = (f16)(a7 + c7);
    *(f16x8*)(OUT + (((size_t)node << 6) + (l << 3))) = r;
}

// ---------------- MFMA GEMM over virtually-concatenated parts ----------------
// out[N,COLS-ish] = ACT( sum_steps A_s[N,32] @ Wstep_s[32,COLS] + addX + bias )
// ACT: 0 none, 1 sigmoid, 2 tanh,
//      4 fused GRU-h0 (COLS=128: z=sig(lo), t=tanh(hi), out[N,64] = (1-z)*t),
//      5 fused z|R*h  (COLS=128: out[N,64]=sig(lo)=z, out2[N,64]=sig(hi)*hmul),
//      6 fused GRU combine+relu (COLS=64: t=tanh(v), z=zin, out=relu(z*hmul+(1-z)*t))
template <int STEPS, int COLS, int ACT>
__global__ __launch_bounds__(256) void mfma_gemm(
    const f16* __restrict__ p0, const f16* __restrict__ p1, const f16* __restrict__ p2,
    const f16* __restrict__ p3, const f16* __restrict__ p4, const f16* __restrict__ xcat,
    const f16* __restrict__ wstep, const f16* __restrict__ addX,
    const float* __restrict__ biasLo, const float* __restrict__ biasHi,
    f16* __restrict__ out, const f16* __restrict__ hmul, f16* __restrict__ out2,
    const f16* __restrict__ zin)
{
    __shared__ f16 As[64][40];     // [row][k], pad 40 halves
    __shared__ f16 Ws[COLS][40];   // [col][k]
    const int row0 = blockIdx.x * 64;
    const int tid = threadIdx.x;
    const int wave = tid >> 6, lane = tid & 63;
    const int lr = lane & 15, lk = lane >> 4;
    const int ka = lk << 3;

    constexpr int RT = (COLS == 128) ? 4 : 2;
    f32x4 acc[RT][2] = {};

    const f16* parts[5] = { p0, p1, p2, p3, p4 };

    #pragma unroll
    for (int s = 0; s < STEPS; ++s) {
        __syncthreads();
        {   // stage A tile: 64 rows x 32 halves
            int r = tid >> 2, seg = tid & 3;
            int grow = row0 + r;
            const f16* srcp = (s < 10)
                ? parts[s >> 1] + (((size_t)grow << 6) + ((s & 1) << 5) + (seg << 3))
                : xcat + (((size_t)grow << 5) + (seg << 3));
            int4 v = (grow < N_NODES) ? *(const int4*)srcp : make_int4(0, 0, 0, 0);
            *(int4*)&As[r][seg << 3] = v;
        }
        {   // stage W tile: COLS x 32 halves
            for (int q = tid; q < COLS * 4; q += 256) {
                int c = q >> 2, seg = q & 3;
                *(int4*)&Ws[c][seg << 3] =
                    *(const int4*)(wstep + (((size_t)(s * COLS + c) << 5) + (seg << 3)));
            }
        }
        __syncthreads();
        if (COLS == 128) {
            f16x8 b0 = *(const f16x8*)&Ws[wave * 32 + lr][ka];
            f16x8 b1 = *(const f16x8*)&Ws[wave * 32 + 16 + lr][ka];
            #pragma unroll
            for (int rt = 0; rt < RT; ++rt) {
                f16x8 a = *(const f16x8*)&As[rt * 16 + lr][ka];
                acc[rt][0] = __builtin_amdgcn_mfma_f32_16x16x32_f16(a, b0, acc[rt][0], 0, 0, 0);
                acc[rt][1] = __builtin_amdgcn_mfma_f32_16x16x32_f16(a, b1, acc[rt][1], 0, 0, 0);
            }
        } else {
            f16x8 b0 = *(const f16x8*)&Ws[(wave & 1) * 32 + lr][ka];
            f16x8 b1 = *(const f16x8*)&Ws[(wave & 1) * 32 + 16 + lr][ka];
            #pragma unroll
            for (int rt = 0; rt < RT; ++rt) {
                f16x8 a = *(const f16x8*)&As[(wave >> 1) * 32 + rt * 16 + lr][ka];
                acc[rt][0] = __builtin_amdgcn_mfma_f32_16x16x32_f16(a, b0, acc[rt][0], 0, 0, 0);
                acc[rt][1] = __builtin_amdgcn_mfma_f32_16x16x32_f16(a, b1, acc[rt][1], 0, 0, 0);
            }
        }
    }
    // D layout: col=lane&15 (+16*ct+32*wavepart), row=(lane>>4)*4+reg
    if constexpr (ACT == 4) {
        __shared__ float zbuf[64][65];
        float treg[RT][2][4];
        #pragma unroll
        for (int rt = 0; rt < RT; ++rt)
            #pragma unroll
            for (int ct = 0; ct < 2; ++ct) {
                int col = wave * 32 + ct * 16 + lr;
                #pragma unroll
                for (int j = 0; j < 4; ++j) {
                    int r = rt * 16 + lk * 4 + j;
                    float v = acc[rt][ct][j] + ((col < 64) ? biasLo[col] : biasHi[col - 64]);
                    if (col < 64) zbuf[r][col] = sigf(v);
                    else          treg[rt][ct][j] = tanhf(v);
                }
            }
        __syncthreads();
        #pragma unroll
        for (int rt = 0; rt < RT; ++rt)
            #pragma unroll
            for (int ct = 0; ct < 2; ++ct) {
                int col = wave * 32 + ct * 16 + lr;
                if (col < 64) continue;
                #pragma unroll
                for (int j = 0; j < 4; ++j) {
                    int r = rt * 16 + lk * 4 + j;
                    int grow = row0 + r;
                    if (grow >= N_NODES) continue;
                    float h = (1.f - zbuf[r][col - 64]) * treg[rt][ct][j];
                    out[((size_t)grow << 6) + (col - 64)] = (f16)h;
                }
            }
    } else if constexpr (ACT == 5) {
        #pragma unroll
        for (int rt = 0; rt < RT; ++rt)
            #pragma unroll
            for (int ct = 0; ct < 2; ++ct) {
                int col = wave * 32 + ct * 16 + lr;
                #pragma unroll
                for (int j = 0; j < 4; ++j) {
                    int grow = row0 + rt * 16 + lk * 4 + j;
                    if (grow >= N_NODES) continue;
                    float v = acc[rt][ct][j];
                    if (addX) v += (float)addX[((size_t)grow << 7) + col];
                    v += (col < 64) ? biasLo[col] : biasHi[col - 64];
                    float sg = sigf(v);
                    if (col < 64)
                        out[((size_t)grow << 6) + col] = (f16)sg;   // z gate
                    else
                        out2[((size_t)grow << 6) + (col - 64)] =    // g = R*h
                            (f16)(sg * (float)hmul[((size_t)grow << 6) + (col - 64)]);
                }
            }
    } else {
        #pragma unroll
        for (int rt = 0; rt < RT; ++rt) {
            int rbase = (COLS == 128) ? rt * 16 : (wave >> 1) * 32 + rt * 16;
            #pragma unroll
            for (int ct = 0; ct < 2; ++ct) {
                int col = ((COLS == 128) ? wave * 32 : (wave & 1) * 32) + ct * 16 + lr;
                #pragma unroll
                for (int j = 0; j < 4; ++j) {
                    int grow = row0 + rbase + lk * 4 + j;
                    if (grow >= N_NODES) continue;
                    float v = acc[rt][ct][j];
                    if (addX)   v += (float)addX[(size_t)grow * COLS + col];
                    if (biasLo) v += (col < 64) ? biasLo[col] : biasHi[col - 64];
                    if (ACT == 1)      v = sigf(v);
                    else if (ACT == 2) v = tanhf(v);
                    else if (ACT == 6) {
                        float t = tanhf(v);
                        float z = (float)zin[((size_t)grow << 6) + col];
                        float hv = (float)hmul[((size_t)grow << 6) + col];
                        v = fmaxf(z * hv + (1.f - z) * t, 0.f);
                    }
                    out[(size_t)grow * COLS + col] = (f16)v;
                }
            }
        }
    }
}

// ---------------- fused enc1 (K=10 VALU GEMM + GRU combine) ----------------
__global__ __launch_bounds__(256) void enc1_kernel(const f16* __restrict__ xcat,
                                                   const float* __restrict__ We1,
                                                   const float* __restrict__ b,
                                                   f16* __restrict__ h1, f16* __restrict__ h1r)
{
    int node = (blockIdx.x << 2) + (threadIdx.x >> 6);
    int lane = threadIdx.x & 63;
    float az = b[lane], at = b[128 + lane];
    #pragma unroll
    for (int k = 0; k < 10; ++k) {
        float xv = (float)xcat[((size_t)node << 5) + k];
        az += xv * We1[k * 128 + lane];
        at += xv * We1[k * 128 + 64 + lane];
    }
    float z = sigf(az), t = tanhf(at);
    float h = (1.f - z) * t;
    size_t o = ((size_t)node << 6) + lane;
    h1[o] = (f16)h;
    h1r[o] = (f16)fmaxf(h, 0.f);
}

// ---------------- elementwise glue ----------------

__global__ __launch_bounds__(256) void final_kernel(const f16* __restrict__ zb, const f16* __restrict__ gT,
                                                    const f16* __restrict__ h2,
                                                    const float* __restrict__ lW, const float* __restrict__ lb,
                                                    float* __restrict__ out)
{
    int node = (blockIdx.x << 2) + (threadIdx.x >> 6);
    int lane = threadIdx.x & 63;
    size_t i = ((size_t)node << 6) + lane;
    float z = (float)zb[i];
    float d = z * (float)h2[i] + (1.f - z) * (float)gT[i];
    float s0 = d * lW[lane * 2];
    float s1 = d * lW[lane * 2 + 1];
    #pragma unroll
    for (int off = 32; off > 0; off >>= 1) {
        s0 += __shfl_down(s0, off);
        s1 += __shfl_down(s1, off);
    }
    if (lane == 0) {
        out[node * 2]     = s0 + lb[0];
        out[node * 2 + 1] = s1 + lb[1];
    }
}

// ---------------- driver ----------------

extern "C" void kernel_launch(void* const* d_in, const int* in_sizes, int n_in,
                              void* d_out, int out_size, void* d_ws, size_t ws_size,
                              hipStream_t stream)
{
    (void)in_sizes; (void)n_in; (void)out_size;
    const float* x   = (const float*)d_in[0];
    const int*  eidx = (const int*)d_in[1];
    const float* ew  = (const float*)d_in[2];
    const float* e1W = (const float*)d_in[3];
    const float* e1b = (const float*)d_in[4];
    const float* e2W = (const float*)d_in[5];
    const float* e2b = (const float*)d_in[6];
    const float* d1W = (const float*)d_in[7];
    const float* d1b = (const float*)d_in[8];
    const float* d2W = (const float*)d_in[9];
    const float* d2b = (const float*)d_in[10];
    const float* lW  = (const float*)d_in[11];
    const float* lb  = (const float*)d_in[12];
    const int* src = eidx;
    const int* dst = eidx + N_EDGES;
    const int N = N_NODES, E = N_EDGES;

    char* p = (char*)d_ws;
    auto carve = [&](size_t bytes) { char* r = p; p += (bytes + 255) & ~(size_t)255; return r; };
    int*   cntO  = (int*)carve((size_t)2 * N * 4);
    int*   cntI  = cntO + N;
    int*   rpO   = (int*)carve((size_t)(N + 1) * 4);
    int*   rpI   = (int*)carve((size_t)(N + 1) * 4);
    int*   slotO = (int*)carve((size_t)E * 4);   // later reused as adjO
    int*   slotI = (int*)carve((size_t)E * 4);   // later reused as adjI
    int2*  adj2O = (int2*)carve((size_t)E * 8);
    int2*  adj2I = (int2*)carve((size_t)E * 8);
    float* do_inv = (float*)carve((size_t)N * 4);
    float* di_inv = (float*)carve((size_t)N * 4);
    f16*   xcat = (f16*)carve((size_t)N * 32 * 2);
    size_t NH = (size_t)N * 64 * 2;
    f16* h1  = (f16*)carve(NH);
    f16* h1r = (f16*)carve(NH);   // reused as hA after enc2
    f16* h2  = (f16*)carve(NH);
    f16* g   = (f16*)carve(NH);
    f16* gT  = (f16*)carve(NH);
    f16* t0  = (f16*)carve(NH);   // t1o
    f16* t1  = (f16*)carve(NH);   // s2o
    f16* t2  = (f16*)carve(NH);   // t1i
    f16* t3  = (f16*)carve(NH);   // s2i
    f16* zb  = (f16*)carve(NH);                      // z gate [N,64]
    f16* zz128 = (f16*)carve((size_t)N * 128 * 2);   // dec2 partial [N,128]
    f16* wE2   = (f16*)carve((size_t)10 * 128 * 32 * 2);
    f16* wD1zr = (f16*)carve((size_t)11 * 128 * 32 * 2);
    f16* wD1c  = (f16*)carve((size_t)11 * 64 * 32 * 2);
    f16* wD2zrA = (f16*)carve((size_t)10 * 128 * 32 * 2);
    f16* wD2zrB = (f16*)carve((size_t)10 * 128 * 32 * 2);
    f16* wD2cA  = (f16*)carve((size_t)10 * 64 * 32 * 2);
    f16* wD2cB  = (f16*)carve((size_t)10 * 64 * 32 * 2);
    float* We1  = (float*)carve((size_t)1280 * 4);

    size_t needed = (size_t)(p - (char*)d_ws);
    if (needed > ws_size) return;   // clean failure (diagnosable) instead of fault

    const int eg = (E + 255) / 256;
    const int ng = (N + 255) / 256;
    const int GB = 25000;           // N*64/256 elementwise grid; N/4 node-wave grid

    // --- graph prep ---
    hipMemsetAsync(cntO, 0, (size_t)2 * N * 4, stream);
    count_kernel<<<eg, 256, 0, stream>>>(src, dst, cntO, cntI, slotO, slotI);
    scan2_kernel<<<2, 1024, 0, stream>>>(cntO, rpO, cntI, rpI, N);
    fill_kernel<<<eg, 256, 0, stream>>>(src, dst, ew, rpO, rpI, slotO, slotI, adj2O, adj2I);
    int* adjO = slotO;  // slot arrays dead after fill; reuse as compact adjacency
    int* adjI = slotI;
    finalize_kernel<<<ng, 256, 0, stream>>>(rpO, adj2O, adjO, di_inv, rpI, adj2I, adjI, do_inv);

    // --- weight prep ---
    auto wprep = [&](const float* W, int C, int rowBase, int gLo, int gHi, int COLS, int XS, f16* o) {
        int total = (10 + XS) * COLS * 32;
        prep_w<<<(total + 255) / 256, 256, 0, stream>>>(W, C, rowBase, gLo, gHi, COLS, XS, o);
    };
    wprep(e2W, 128, 0,  0, 2, 128, 0, wE2);
    wprep(d1W, 66,  2,  0, 1, 128, 1, wD1zr);
    wprep(d1W, 66,  2,  2, -1, 64, 1, wD1c);
    wprep(d2W, 128, 0,  0, 1, 128, 0, wD2zrA);
    wprep(d2W, 128, 64, 0, 1, 128, 0, wD2zrB);
    wprep(d2W, 128, 0,  2, -1, 64, 0, wD2cA);
    wprep(d2W, 128, 64, 2, -1, 64, 0, wD2cB);
    prep_enc1w<<<5, 256, 0, stream>>>(e1W, We1);

    // --- x features + 2-channel Chebyshev basis (folded: pure P hops) ---
    xcat_init<<<(N * 32 + 255) / 256, 256, 0, stream>>>(x, xcat);
    prop2_kernel<<<ng, 256, 0, stream>>>(rpO, adjO, do_inv, xcat, 0, 2);  // t1o
    prop2_kernel<<<ng, 256, 0, stream>>>(rpO, adjO, do_inv, xcat, 2, 4);  // s2o
    prop2_kernel<<<ng, 256, 0, stream>>>(rpI, adjI, di_inv, xcat, 0, 6);  // t1i
    prop2_kernel<<<ng, 256, 0, stream>>>(rpI, adjI, di_inv, xcat, 6, 8);  // s2i

    const dim3 pg((N + 31) / 32, 2);
    auto props = [&](const f16* u) {  // t0..t3 = (t1o, s2o, t1i, s2i) of u
        prop8<<<pg, 256, 0, stream>>>(rpO, adjO, do_inv, u, t0,
                                      rpI, adjI, di_inv, u, t2);
        prop8<<<pg, 256, 0, stream>>>(rpO, adjO, do_inv, t0, t1,
                                      rpI, adjI, di_inv, t2, t3);
    };
    const int gg = (N + 63) / 64;

    // enc1
    enc1_kernel<<<GB, 256, 0, stream>>>(xcat, We1, e1b, h1, h1r);
    // enc2 (input h1r, h=0): fused GRU-h0 epilogue writes h2 directly
    props(h1r);
    mfma_gemm<10, 128, 4><<<gg, 256, 0, stream>>>(h1r, t0, t1, t2, t3, nullptr, wE2,
                                                  nullptr, e2b, e2b + 128, h2, nullptr, nullptr, nullptr);
    // dec1 (x=xs, h=h1): fused z|R*h epilogue, then fused combine+relu epilogue
    props(h1);
    mfma_gemm<11, 128, 5><<<gg, 256, 0, stream>>>(h1, t0, t1, t2, t3, xcat, wD1zr,
                                                  nullptr, d1b, d1b + 64, zb, h1, g, nullptr);
    props(g);
    mfma_gemm<11, 64, 6><<<gg, 256, 0, stream>>>(g, t0, t1, t2, t3, xcat, wD1c,
                                                 nullptr, d1b + 128, d1b + 128, h1r, h1, nullptr, zb);
    // dec2 (x=hA=h1r, h=h2): K=640 split in halves; partials chained through zz128 / gT
    props(h1r);
    mfma_gemm<10, 128, 0><<<gg, 256, 0, stream>>>(h1r, t0, t1, t2, t3, nullptr, wD2zrA,
                                                  nullptr, nullptr, nullptr, zz128, nullptr, nullptr, nullptr);
    mfma_gemm<10, 64, 0><<<gg, 256, 0, stream>>>(h1r, t0, t1, t2, t3, nullptr, wD2cA,
                                                 nullptr, nullptr, nullptr, gT, nullptr, nullptr, nullptr);
    props(h2);
    mfma_gemm<10, 128, 5><<<gg, 256, 0, stream>>>(h2, t0, t1, t2, t3, nullptr, wD2zrB,
                                                  zz128, d2b, d2b + 64, zb, h2, g, nullptr);
    props(g);
    mfma_gemm<10, 64, 2><<<gg, 256, 0, stream>>>(g, t0, t1, t2, t3, nullptr, wD2cB,
                                                 gT, d2b + 128, d2b + 128, gT, nullptr, nullptr, nullptr);
    final_kernel<<<GB, 256, 0, stream>>>(zb, gT, h2, lW, lb, (float*)d_out);
}

// Round 7
// 1470.496 us; speedup vs baseline: 4.3169x; 1.0064x over previous
//
#include <hip/hip_runtime.h>

#define N_NODES 100000
#define N_EDGES 1600000

typedef _Float16 f16;
typedef _Float16 f16x8 __attribute__((ext_vector_type(8)));
typedef float f32x4 __attribute__((ext_vector_type(4)));

__device__ __forceinline__ float sigf(float x) { return 1.f / (1.f + __expf(-x)); }

// ---------------- graph preprocessing ----------------

__global__ void count_kernel(const int* __restrict__ src, const int* __restrict__ dst,
                             int* __restrict__ cntO, int* __restrict__ cntI,
                             int* __restrict__ slotO, int* __restrict__ slotI)
{
    int i = blockIdx.x * 256 + threadIdx.x;
    if (i >= N_EDGES) return;
    slotO[i] = atomicAdd(&cntO[dst[i]], 1);   // pout CSR grouped by dst
    slotI[i] = atomicAdd(&cntI[src[i]], 1);   // pin CSR grouped by src
}

__global__ __launch_bounds__(1024) void scan2_kernel(const int* __restrict__ cntA, int* __restrict__ rpA,
                                                     const int* __restrict__ cntB, int* __restrict__ rpB,
                                                     int n)
{
    const int* cnt = blockIdx.x ? cntB : cntA;
    int* rp = blockIdx.x ? rpB : rpA;
    __shared__ int wsum[16];
    __shared__ int carry;
    int tid = threadIdx.x, lane = tid & 63, wid = tid >> 6;
    if (tid == 0) { rp[0] = 0; carry = 0; }
    __syncthreads();
    for (int base = 0; base < n; base += 1024) {
        int idx = base + tid;
        int x = (idx < n) ? cnt[idx] : 0;
        #pragma unroll
        for (int off = 1; off < 64; off <<= 1) {
            int y = __shfl_up(x, off);
            if (lane >= off) x += y;
        }
        if (lane == 63) wsum[wid] = x;
        __syncthreads();
        if (wid == 0 && lane < 16) {
            int y = wsum[lane];
            #pragma unroll
            for (int off = 1; off < 16; off <<= 1) {
                int z = __shfl_up(y, off);
                if (lane >= off) y += z;
            }
            wsum[lane] = y;
        }
        __syncthreads();
        int tot = x + (wid ? wsum[wid - 1] : 0) + carry;
        if (idx < n) rp[idx + 1] = tot;
        __syncthreads();
        if (tid == 1023) carry = tot;
        __syncthreads();
    }
}

__global__ void fill_kernel(const int* __restrict__ src, const int* __restrict__ dst,
                            const float* __restrict__ ew,
                            const int* __restrict__ rpO, const int* __restrict__ rpI,
                            const int* __restrict__ slotO, const int* __restrict__ slotI,
                            int2* __restrict__ adj2O, int2* __restrict__ adj2I)
{
    int i = blockIdx.x * 256 + threadIdx.x;
    if (i >= N_EDGES) return;
    int s = src[i], d = dst[i];
    int wb = __float_as_int(ew[i]);
    int2 eo; eo.x = s; eo.y = wb;
    adj2O[rpO[d] + slotO[i]] = eo;
    int2 ei; ei.x = d; ei.y = wb;
    adj2I[rpI[s] + slotI[i]] = ei;
}

// Compact int2 CSR -> int adjacency, and compute inverse degrees in the same sweep.
__global__ void finalize_kernel(const int* __restrict__ rpO, const int2* __restrict__ adj2O,
                                int* __restrict__ adjO, float* __restrict__ di_inv,
                                const int* __restrict__ rpI, const int2* __restrict__ adj2I,
                                int* __restrict__ adjI, float* __restrict__ do_inv)
{
    int n = blockIdx.x * 256 + threadIdx.x;
    if (n >= N_NODES) return;
    float s = 0.f;
    for (int e = rpO[n]; e < rpO[n + 1]; ++e) {
        int2 v = adj2O[e];
        adjO[e] = v.x;
        s += __int_as_float(v.y);
    }
    di_inv[n] = (s > 0.f) ? 1.f / s : 0.f;
    float t = 0.f;
    for (int e = rpI[n]; e < rpI[n + 1]; ++e) {
        int2 v = adj2I[e];
        adjI[e] = v.x;
        t += __int_as_float(v.y);
    }
    do_inv[n] = (t > 0.f) ? 1.f / t : 0.f;
}

// ---------------- weight preprocessing (Chebyshev-folded) ----------------
// Parts: p0=u (W00+W10-W02-W12), p1=t1o (W01), p2=s2o (2*W02), p3=t1i (W11), p4=s2i (2*W12).
// Step s<SA: part p=s/PWA, weight rows rA + (s%PWA)*32 + k32.
// XS step: k<10 -> p=k>>1, row = k&1 (x channels); else 0.
__global__ void prep_w(const float* __restrict__ W, int C, int SA, int PWA, int rA,
                       int gLo, int gHi, int COLS, int XS, f16* __restrict__ outw)
{
    int total = (SA + XS) * COLS * 32;
    int idx = blockIdx.x * 256 + threadIdx.x;
    if (idx >= total) return;
    int k32 = idx & 31;
    int c = (idx >> 5) % COLS;
    int s = (idx >> 5) / COLS;
    int g = (c < 64 || gHi < 0) ? gLo : gHi;
    int col = (c >= 64) ? c - 64 : c;
    int p, r;
    if (s < SA) { p = s / PWA; r = rA + (s % PWA) * 32 + k32; }
    else {
        if (k32 < 10) { p = k32 >> 1; r = k32 & 1; }
        else { outw[idx] = (f16)0.f; return; }
    }
    auto wv = [&](int d, int k) {
        return W[((((size_t)(g * 2 + d) * 3 + k) * C + r) << 6) + col];
    };
    float val;
    if (p == 0)      val = wv(0, 0) + wv(1, 0) - wv(0, 2) - wv(1, 2);
    else if (p == 1) val = wv(0, 1);
    else if (p == 2) val = 2.f * wv(0, 2);
    else if (p == 3) val = wv(1, 1);
    else             val = 2.f * wv(1, 2);
    outw[idx] = (f16)val;
}

// enc1 weights fp32 [10][128]: cols 0-63 gate z(0), 64-127 gate h(2); C=66, x rows 0..1
__global__ void prep_enc1w(const float* __restrict__ W, float* __restrict__ outw)
{
    int idx = blockIdx.x * 256 + threadIdx.x;
    if (idx >= 1280) return;
    int c = idx & 127, k = idx >> 7;
    int g = (c < 64) ? 0 : 2, col = c & 63;
    int p = k >> 1, r = k & 1;
    const int C = 66;
    auto wv = [&](int d, int kk) {
        return W[((((size_t)(g * 2 + d) * 3 + kk) * C + r) << 6) + col];
    };
    float val;
    if (p == 0)      val = wv(0, 0) + wv(1, 0) - wv(0, 2) - wv(1, 2);
    else if (p == 1) val = wv(0, 1);
    else if (p == 2) val = 2.f * wv(0, 2);
    else if (p == 3) val = wv(1, 1);
    else             val = 2.f * wv(1, 2);
    outw[idx] = val;
}

// xcat fp16 [N][32]: cols 0-1 = xs, 2-9 = (t1o, s2o, t1i, s2i), 10-31 zero
__global__ void xcat_init(const float* __restrict__ x, f16* __restrict__ xcat)
{
    int i = blockIdx.x * 256 + threadIdx.x;
    if (i >= N_NODES * 32) return;
    int n = i >> 5, c = i & 31;
    float v = (c < 2) ? x[(size_t)n * 24 + c] : 0.f;  // x[:, :, 0, :] of (4,25000,12,2)
    xcat[i] = (f16)v;
}

// 2-channel pure propagation inside xcat, dual-direction via blockIdx.y
__global__ void prop2d_kernel(const int* __restrict__ rpA, const int* __restrict__ adjA,
                              const float* __restrict__ scA, int cinA, int coutA,
                              const int* __restrict__ rpB, const int* __restrict__ adjB,
                              const float* __restrict__ scB, int cinB, int coutB,
                              f16* __restrict__ xcat)
{
    const int* rp; const int* adj; const float* sc; int cin, cout;
    if (blockIdx.y == 0) { rp = rpA; adj = adjA; sc = scA; cin = cinA; cout = coutA; }
    else                 { rp = rpB; adj = adjB; sc = scB; cin = cinB; cout = coutB; }
    int n = blockIdx.x * 256 + threadIdx.x;
    if (n >= N_NODES) return;
    int beg = rp[n], end = rp[n + 1];
    float a0 = 0.f, a1 = 0.f;
    for (int e = beg; e < end; ++e) {
        int s = adj[e];
        float w = sc[s];
        a0 += w * (float)xcat[((size_t)s << 5) + cin];
        a1 += w * (float)xcat[((size_t)s << 5) + cin + 1];
    }
    xcat[((size_t)n << 5) + cout] = (f16)a0;
    xcat[((size_t)n << 5) + cout + 1] = (f16)a1;
}

// ---------------- propagation: LPN lanes/node, f16x8 loads, dir = blockIdx.y ----------
// LPN=8: 64-ch rows; LPN=16: 128-ch rows. ldu/ldo = strides in halves.
template <int LPN>
__global__ __launch_bounds__(256) void propk(
    const int* __restrict__ rpA, const int* __restrict__ adjA, const float* __restrict__ scA,
    const f16* __restrict__ uA, f16* __restrict__ oA,
    const int* __restrict__ rpB, const int* __restrict__ adjB, const float* __restrict__ scB,
    const f16* __restrict__ uB, f16* __restrict__ oB,
    int ldu, int ldo)
{
    const int* RP; const int* ADJ; const float* SC; const f16* U; f16* OUT;
    if (blockIdx.y == 0) { RP = rpA; ADJ = adjA; SC = scA; U = uA; OUT = oA; }
    else                 { RP = rpB; ADJ = adjB; SC = scB; U = uB; OUT = oB; }
    constexpr int NPB = 256 / LPN;
    int node = blockIdx.x * NPB + (threadIdx.x / LPN);
    int l = threadIdx.x % LPN;
    if (node >= N_NODES) return;
    int b = RP[node], e = RP[node + 1];
    float a[8] = {0.f, 0.f, 0.f, 0.f, 0.f, 0.f, 0.f, 0.f};
    float c[8] = {0.f, 0.f, 0.f, 0.f, 0.f, 0.f, 0.f, 0.f};
    int i = b;
    for (; i + 1 < e; i += 2) {
        int s0 = ADJ[i], s1 = ADJ[i + 1];
        float w0 = SC[s0], w1 = SC[s1];
        f16x8 u0 = *(const f16x8*)(U + (size_t)s0 * ldu + (l << 3));
        f16x8 u1 = *(const f16x8*)(U + (size_t)s1 * ldu + (l << 3));
        #pragma unroll
        for (int j = 0; j < 8; ++j) { a[j] += w0 * (float)u0[j]; c[j] += w1 * (float)u1[j]; }
    }
    if (i < e) {
        int s = ADJ[i];
        float w = SC[s];
        f16x8 u0 = *(const f16x8*)(U + (size_t)s * ldu + (l << 3));
        #pragma unroll
        for (int j = 0; j < 8; ++j) a[j] += w * (float)u0[j];
    }
    f16x8 r;
    #pragma unroll
    for (int j = 0; j < 8; ++j) r[j] = (f16)(a[j] + c[j]);
    *(f16x8*)(OUT + (size_t)node * ldo + (l << 3)) = r;
}

// ---------------- MFMA GEMM over virtually-concatenated parts ----------------
// out = ACT( sum_steps A_s[N,32] @ Wstep_s[32,COLS] + addX + bias )
// Parts: u (lAu, cAu) + 4 t-buffers (lAt, cAt), PWA=SA/5 chunks each; optional xcat step.
// ACT: 0 none, 2 tanh,
//      4 fused GRU-h0 (COLS=128: z=sig(lo), t=tanh(hi), out[.,os]+col-64 = (1-z)*t),
//      5 fused z|R*h  (COLS=128: out[N,64]=sig(lo)=z, out2[N,64]=sig(hi)*hmul[.,hs]),
//      6 fused GRU combine+relu (COLS=64: out[.,os] = relu(zin*hmul + (1-zin)*tanh(v)))
template <int SA, int XS, int COLS, int ACT>
__global__ __launch_bounds__(256) void mfma_gemm(
    const f16* __restrict__ uA, const f16* __restrict__ tA0, const f16* __restrict__ tA1,
    const f16* __restrict__ tA2, const f16* __restrict__ tA3,
    int lAu, int cAu, int lAt, int cAt,
    const f16* __restrict__ xcat, const f16* __restrict__ wstep,
    const f16* __restrict__ addX,
    const float* __restrict__ biasLo, const float* __restrict__ biasHi,
    f16* __restrict__ out, int os,
    const f16* __restrict__ hmul, int hs,
    f16* __restrict__ out2, const f16* __restrict__ zin)
{
    __shared__ f16 As[64][40];     // [row][k], pad 40 halves
    __shared__ f16 Ws[COLS][40];   // [col][k]
    const int row0 = blockIdx.x * 64;
    const int tid = threadIdx.x;
    const int wave = tid >> 6, lane = tid & 63;
    const int lr = lane & 15, lk = lane >> 4;
    const int ka = lk << 3;
    constexpr int RT = (COLS == 128) ? 4 : 2;
    constexpr int PWA = SA / 5;
    constexpr int STEPS = SA + XS;
    f32x4 acc[RT][2] = {};
    const f16* tA[4] = { tA0, tA1, tA2, tA3 };

    #pragma unroll
    for (int s = 0; s < STEPS; ++s) {
        __syncthreads();
        {   // stage A tile: 64 rows x 32 halves
            int r = tid >> 2, seg = tid & 3;
            int grow = row0 + r;
            const f16* srcp;
            if (s < SA) {
                int p = s / PWA, ch = s % PWA;
                const f16* base = (p == 0) ? uA : tA[p - 1];
                int ld = (p == 0) ? lAu : lAt;
                int co = (p == 0) ? cAu : cAt;
                srcp = base + (size_t)grow * ld + co + ch * 32 + (seg << 3);
            } else {
                srcp = xcat + (((size_t)grow) << 5) + (seg << 3);
            }
            int4 v = (grow < N_NODES) ? *(const int4*)srcp : make_int4(0, 0, 0, 0);
            *(int4*)&As[r][seg << 3] = v;
        }
        for (int q = tid; q < COLS * 4; q += 256) {
            int c = q >> 2, seg = q & 3;
            *(int4*)&Ws[c][seg << 3] =
                *(const int4*)(wstep + (((size_t)(s * COLS + c)) << 5) + (seg << 3));
        }
        __syncthreads();
        if (COLS == 128) {
            f16x8 b0 = *(const f16x8*)&Ws[wave * 32 + lr][ka];
            f16x8 b1 = *(const f16x8*)&Ws[wave * 32 + 16 + lr][ka];
            #pragma unroll
            for (int rt = 0; rt < RT; ++rt) {
                f16x8 a = *(const f16x8*)&As[rt * 16 + lr][ka];
                acc[rt][0] = __builtin_amdgcn_mfma_f32_16x16x32_f16(a, b0, acc[rt][0], 0, 0, 0);
                acc[rt][1] = __builtin_amdgcn_mfma_f32_16x16x32_f16(a, b1, acc[rt][1], 0, 0, 0);
            }
        } else {
            f16x8 b0 = *(const f16x8*)&Ws[(wave & 1) * 32 + lr][ka];
            f16x8 b1 = *(const f16x8*)&Ws[(wave & 1) * 32 + 16 + lr][ka];
            #pragma unroll
            for (int rt = 0; rt < RT; ++rt) {
                f16x8 a = *(const f16x8*)&As[(wave >> 1) * 32 + rt * 16 + lr][ka];
                acc[rt][0] = __builtin_amdgcn_mfma_f32_16x16x32_f16(a, b0, acc[rt][0], 0, 0, 0);
                acc[rt][1] = __builtin_amdgcn_mfma_f32_16x16x32_f16(a, b1, acc[rt][1], 0, 0, 0);
            }
        }
    }
    // D layout: col=lane&15 (+16*ct+32*wavepart), row=(lane>>4)*4+reg
    if constexpr (ACT == 4) {
        __shared__ float zbuf[64][65];
        float treg[RT][2][4];
        #pragma unroll
        for (int rt = 0; rt < RT; ++rt)
            #pragma unroll
            for (int ct = 0; ct < 2; ++ct) {
                int col = wave * 32 + ct * 16 + lr;
                #pragma unroll
                for (int j = 0; j < 4; ++j) {
                    int r = rt * 16 + lk * 4 + j;
                    float v = acc[rt][ct][j] + ((col < 64) ? biasLo[col] : biasHi[col - 64]);
                    if (col < 64) zbuf[r][col] = sigf(v);
                    else          treg[rt][ct][j] = tanhf(v);
                }
            }
        __syncthreads();
        #pragma unroll
        for (int rt = 0; rt < RT; ++rt)
            #pragma unroll
            for (int ct = 0; ct < 2; ++ct) {
                int col = wave * 32 + ct * 16 + lr;
                if (col < 64) continue;
                #pragma unroll
                for (int j = 0; j < 4; ++j) {
                    int r = rt * 16 + lk * 4 + j;
                    int grow = row0 + r;
                    if (grow >= N_NODES) continue;
                    float h = (1.f - zbuf[r][col - 64]) * treg[rt][ct][j];
                    out[(size_t)grow * os + (col - 64)] = (f16)h;
                }
            }
    } else if constexpr (ACT == 5) {
        #pragma unroll
        for (int rt = 0; rt < RT; ++rt)
            #pragma unroll
            for (int ct = 0; ct < 2; ++ct) {
                int col = wave * 32 + ct * 16 + lr;
                #pragma unroll
                for (int j = 0; j < 4; ++j) {
                    int grow = row0 + rt * 16 + lk * 4 + j;
                    if (grow >= N_NODES) continue;
                    float v = acc[rt][ct][j] + ((col < 64) ? biasLo[col] : biasHi[col - 64]);
                    float sg = sigf(v);
                    if (col < 64)
                        out[((size_t)grow << 6) + col] = (f16)sg;   // z gate
                    else
                        out2[((size_t)grow << 6) + (col - 64)] =    // g = R*h
                            (f16)(sg * (float)hmul[(size_t)grow * hs + (col - 64)]);
                }
            }
    } else {
        #pragma unroll
        for (int rt = 0; rt < RT; ++rt) {
            int rbase = (COLS == 128) ? rt * 16 : (wave >> 1) * 32 + rt * 16;
            #pragma unroll
            for (int ct = 0; ct < 2; ++ct) {
                int col = ((COLS == 128) ? wave * 32 : (wave & 1) * 32) + ct * 16 + lr;
                #pragma unroll
                for (int j = 0; j < 4; ++j) {
                    int grow = row0 + rbase + lk * 4 + j;
                    if (grow >= N_NODES) continue;
                    float v = acc[rt][ct][j];
                    if (addX)   v += (float)addX[((size_t)grow << 6) + col];
                    if (biasLo) v += (col < 64) ? biasLo[col] : biasHi[col - 64];
                    if (ACT == 2) v = tanhf(v);
                    else if (ACT == 6) {
                        float t = tanhf(v);
                        float z = (float)zin[((size_t)grow << 6) + col];
                        float hv = (float)hmul[(size_t)grow * hs + col];
                        v = fmaxf(z * hv + (1.f - z) * t, 0.f);
                    }
                    out[(size_t)grow * os + col] = (f16)v;
                }
            }
        }
    }
}

// ---------------- fused enc1 (K=10 VALU GEMM + GRU combine) -> c1 = relu(h)||h ------
__global__ __launch_bounds__(256) void enc1_kernel(const f16* __restrict__ xcat,
                                                   const float* __restrict__ We1,
                                                   const float* __restrict__ b,
                                                   f16* __restrict__ c1)
{
    int node = (blockIdx.x << 2) + (threadIdx.x >> 6);
    int lane = threadIdx.x & 63;
    float az = b[lane], at = b[128 + lane];
    #pragma unroll
    for (int k = 0; k < 10; ++k) {
        float xv = (float)xcat[((size_t)node << 5) + k];
        az += xv * We1[k * 128 + lane];
        at += xv * We1[k * 128 + 64 + lane];
    }
    float z = sigf(az), t = tanhf(at);
    float h = (1.f - z) * t;
    size_t o = (size_t)node * 128 + lane;
    c1[o] = (f16)fmaxf(h, 0.f);   // h1r half
    c1[o + 64] = (f16)h;          // h1 half
}

// ---------------- final: GRU combine + linear [64->2] ----------------
__global__ __launch_bounds__(256) void final_kernel(const f16* __restrict__ zb, const f16* __restrict__ gT,
                                                    const f16* __restrict__ h2, // stride 128
                                                    const float* __restrict__ lW, const float* __restrict__ lb,
                                                    float* __restrict__ out)
{
    int node = (blockIdx.x << 2) + (threadIdx.x >> 6);
    int lane = threadIdx.x & 63;
    size_t i = ((size_t)node << 6) + lane;
    float z = (float)zb[i];
    float d = z * (float)h2[(size_t)node * 128 + lane] + (1.f - z) * (float)gT[i];
    float s0 = d * lW[lane * 2];
    float s1 = d * lW[lane * 2 + 1];
    #pragma unroll
    for (int off = 32; off > 0; off >>= 1) {
        s0 += __shfl_down(s0, off);
        s1 += __shfl_down(s1, off);
    }
    if (lane == 0) {
        out[node * 2]     = s0 + lb[0];
        out[node * 2 + 1] = s1 + lb[1];
    }
}

// ---------------- driver ----------------

extern "C" void kernel_launch(void* const* d_in, const int* in_sizes, int n_in,
                              void* d_out, int out_size, void* d_ws, size_t ws_size,
                              hipStream_t stream)
{
    (void)in_sizes; (void)n_in; (void)out_size;
    const float* x   = (const float*)d_in[0];
    const int*  eidx = (const int*)d_in[1];
    const float* ew  = (const float*)d_in[2];
    const float* e1W = (const float*)d_in[3];
    const float* e1b = (const float*)d_in[4];
    const float* e2W = (const float*)d_in[5];
    const float* e2b = (const float*)d_in[6];
    const float* d1W = (const float*)d_in[7];
    const float* d1b = (const float*)d_in[8];
    const float* d2W = (const float*)d_in[9];
    const float* d2b = (const float*)d_in[10];
    const float* lW  = (const float*)d_in[11];
    const float* lb  = (const float*)d_in[12];
    const int* src = eidx;
    const int* dst = eidx + N_EDGES;
    const int N = N_NODES, E = N_EDGES;

    char* p = (char*)d_ws;
    auto carve = [&](size_t bytes) { char* r = p; p += (bytes + 255) & ~(size_t)255; return r; };
    size_t NC = (size_t)N * 128 * 2;             // [N,128] f16 = 25.6 MB
    size_t NH = (size_t)N * 64 * 2;              // [N,64]  f16 = 12.8 MB
    int*   cntO  = (int*)carve((size_t)2 * N * 4);
    int*   cntI  = cntO + N;
    int*   rpO   = (int*)carve((size_t)(N + 1) * 4);
    int*   rpI   = (int*)carve((size_t)(N + 1) * 4);
    int*   slotO = (int*)carve((size_t)E * 4);   // reused as adjO after fill
    int*   slotI = (int*)carve((size_t)E * 4);   // reused as adjI
    char*  uni   = carve((size_t)2 * E * 8);     // adj2O|adj2I during build; ct0 after
    int2*  adj2O = (int2*)uni;
    int2*  adj2I = (int2*)(uni + (size_t)E * 8);
    f16*   ct0   = (f16*)uni;                    // [N,128] (25.6 MB == 2*E*8)
    f16*   ct1   = (f16*)carve(NC);
    f16*   ct2   = (f16*)carve(NC);
    f16*   ct3   = (f16*)carve(NC);
    float* do_inv = (float*)carve((size_t)N * 4);
    float* di_inv = (float*)carve((size_t)N * 4);
    f16*   xcat = (f16*)carve((size_t)N * 32 * 2);
    f16*   c1   = (f16*)carve(NC);   // h1r || h1
    f16*   c2   = (f16*)carve(NC);   // hA || h2
    f16*   g    = (f16*)carve(NH);   // R*h
    f16*   gT   = (f16*)carve(NH);   // candidate partial / output
    f16*   zb   = (f16*)carve(NH);   // z gate
    f16* wE2   = (f16*)carve((size_t)10 * 128 * 32 * 2);
    f16* wD1zr = (f16*)carve((size_t)11 * 128 * 32 * 2);
    f16* wD1c  = (f16*)carve((size_t)11 * 64 * 32 * 2);
    f16* wD2zr = (f16*)carve((size_t)20 * 128 * 32 * 2);
    f16* wD2cA = (f16*)carve((size_t)10 * 64 * 32 * 2);
    f16* wD2cB = (f16*)carve((size_t)10 * 64 * 32 * 2);
    float* We1 = (float*)carve((size_t)1280 * 4);

    size_t needed = (size_t)(p - (char*)d_ws);
    if (needed > ws_size) return;   // clean failure (diagnosable) instead of fault

    const int eg = (E + 255) / 256;
    const int ng = (N + 255) / 256;
    const int GB = 25000;           // N/4 node-wave grid

    // --- graph prep ---
    hipMemsetAsync(cntO, 0, (size_t)2 * N * 4, stream);
    count_kernel<<<eg, 256, 0, stream>>>(src, dst, cntO, cntI, slotO, slotI);
    scan2_kernel<<<2, 1024, 0, stream>>>(cntO, rpO, cntI, rpI, N);
    fill_kernel<<<eg, 256, 0, stream>>>(src, dst, ew, rpO, rpI, slotO, slotI, adj2O, adj2I);
    int* adjO = slotO;
    int* adjI = slotI;
    finalize_kernel<<<ng, 256, 0, stream>>>(rpO, adj2O, adjO, di_inv, rpI, adj2I, adjI, do_inv);

    // --- weight prep ---
    auto wprep = [&](const float* W, int C, int SA, int PWA, int rA,
                     int gLo, int gHi, int COLS, int XS, f16* o) {
        int total = (SA + XS) * COLS * 32;
        prep_w<<<(total + 255) / 256, 256, 0, stream>>>(W, C, SA, PWA, rA, gLo, gHi, COLS, XS, o);
    };
    wprep(e2W, 128, 10, 2, 0,  0,  2, 128, 0, wE2);
    wprep(d1W, 66,  10, 2, 2,  0,  1, 128, 1, wD1zr);
    wprep(d1W, 66,  10, 2, 2,  2, -1,  64, 1, wD1c);
    wprep(d2W, 128, 20, 4, 0,  0,  1, 128, 0, wD2zr);
    wprep(d2W, 128, 10, 2, 0,  2, -1,  64, 0, wD2cA);
    wprep(d2W, 128, 10, 2, 64, 2, -1,  64, 0, wD2cB);
    prep_enc1w<<<5, 256, 0, stream>>>(e1W, We1);

    // --- x features + 2-channel Chebyshev basis (pure P hops, both dirs batched) ---
    xcat_init<<<(N * 32 + 255) / 256, 256, 0, stream>>>(x, xcat);
    dim3 ng2(ng, 2);
    prop2d_kernel<<<ng2, 256, 0, stream>>>(rpO, adjO, do_inv, 0, 2,
                                           rpI, adjI, di_inv, 0, 6, xcat);
    prop2d_kernel<<<ng2, 256, 0, stream>>>(rpO, adjO, do_inv, 2, 4,
                                           rpI, adjI, di_inv, 6, 8, xcat);

    auto props128 = [&](const f16* u) {   // ct0..ct3 = (t1o, s2o, t1i, s2i) of [N,128] u
        dim3 pg(N / 16, 2);
        propk<16><<<pg, 256, 0, stream>>>(rpO, adjO, do_inv, u, ct0,
                                          rpI, adjI, di_inv, u, ct2, 128, 128);
        propk<16><<<pg, 256, 0, stream>>>(rpO, adjO, do_inv, ct0, ct1,
                                          rpI, adjI, di_inv, ct2, ct3, 128, 128);
    };
    auto props64 = [&](const f16* u) {    // ct cols 0-63 = parts of [N,64] u
        dim3 pg(N / 32, 2);
        propk<8><<<pg, 256, 0, stream>>>(rpO, adjO, do_inv, u, ct0,
                                         rpI, adjI, di_inv, u, ct2, 64, 128);
        propk<8><<<pg, 256, 0, stream>>>(rpO, adjO, do_inv, ct0, ct1,
                                         rpI, adjI, di_inv, ct2, ct3, 128, 128);
    };
    const int gg = (N + 63) / 64;

    // enc1 -> c1 = relu(h1)||h1
    enc1_kernel<<<GB, 256, 0, stream>>>(xcat, We1, e1b, c1);
    // combined props of (h1r, h1)
    props128(c1);
    // enc2 (u = h1r half, coff 0): fused GRU-h0 writes h2 into c2 cols 64-127
    mfma_gemm<10, 0, 128, 4><<<gg, 256, 0, stream>>>(
        c1, ct0, ct1, ct2, ct3, 128, 0, 128, 0, nullptr, wE2,
        nullptr, e2b, e2b + 128, c2 + 64, 128, nullptr, 0, nullptr, nullptr);
    // dec1 z|R (u = h1 half, coff 64): z -> zb, g = R*h1
    mfma_gemm<10, 1, 128, 5><<<gg, 256, 0, stream>>>(
        c1, ct0, ct1, ct2, ct3, 128, 64, 128, 64, xcat, wD1zr,
        nullptr, d1b, d1b + 64, zb, 64, c1 + 64, 128, g, nullptr);
    // candidate props of g1 into ct cols 0-63
    props64(g);
    // dec1 candidate: fused combine+relu writes hA into c2 cols 0-63
    mfma_gemm<10, 1, 64, 6><<<gg, 256, 0, stream>>>(
        g, ct0, ct1, ct2, ct3, 64, 0, 128, 0, xcat, wD1c,
        nullptr, d1b + 128, d1b + 128, c2, 128, c1 + 64, 128, nullptr, zb);
    // combined props of (hA, h2)
    props128(c2);
    // dec2 z|R: single K=640 GEMM (PW=4); z -> zb, g = R*h2
    mfma_gemm<20, 0, 128, 5><<<gg, 256, 0, stream>>>(
        c2, ct0, ct1, ct2, ct3, 128, 0, 128, 0, nullptr, wD2zr,
        nullptr, d2b, d2b + 64, zb, 64, c2 + 64, 128, g, nullptr);
    // dec2 candidate part A (hA rows) -> gT partial
    mfma_gemm<10, 0, 64, 0><<<gg, 256, 0, stream>>>(
        c2, ct0, ct1, ct2, ct3, 128, 0, 128, 0, nullptr, wD2cA,
        nullptr, nullptr, nullptr, gT, 64, nullptr, 0, nullptr, nullptr);
    // candidate props of g2 into ct cols 0-63
    props64(g);
    // dec2 candidate part B (g2 rows) + bias + tanh -> gT
    mfma_gemm<10, 0, 64, 2><<<gg, 256, 0, stream>>>(
        g, ct0, ct1, ct2, ct3, 64, 0, 128, 0, nullptr, wD2cB,
        gT, d2b + 128, d2b + 128, gT, 64, nullptr, 0, nullptr, nullptr);
    final_kernel<<<GB, 256, 0, stream>>>(zb, gT, c2 + 64, lW, lb, (float*)d_out);
}